// Round 15
// baseline (823.303 us; speedup 1.0000x reference)
//
#include <hip/hip_runtime.h>

typedef unsigned short u16;
typedef __attribute__((ext_vector_type(8))) short short8;
typedef __attribute__((ext_vector_type(4))) float floatx4;

constexpr int N_ = 20000;
constexpr int E_ = 400000;

#define DEV __device__ __forceinline__

DEV float bf2f(u16 u) { union { unsigned int i; float f; } x; x.i = ((unsigned int)u) << 16; return x.f; }
DEV u16 f2bf(float f) {
    union { unsigned int i; float f; } x; x.f = f;
    unsigned int i = x.i;
    unsigned int r = i + 0x7FFFu + ((i >> 16) & 1u);
    return (u16)(r >> 16);
}
// order-preserving float<->uint for atomicMax (unsigned) [slow path only]
DEV unsigned int fenc(float f) {
    unsigned int i = __float_as_uint(f);
    return (i & 0x80000000u) ? ~i : (i | 0x80000000u);
}
DEV float fdec(unsigned int u) {
    return (u & 0x80000000u) ? __uint_as_float(u ^ 0x80000000u) : __uint_as_float(~u);
}

// ---------------------------------------------------------------- zero a uint span
__global__ __launch_bounds__(256) void k_zero(unsigned int* p, int n) {
    int i = blockIdx.x * 256 + threadIdx.x;
    if (i < n) p[i] = 0u;
}

// ================================================================ FAST PATH
// ---------------------------------------------------------------- prep0: composites M_r/M_ea + bias constants
__global__ __launch_bounds__(256) void k_prep0(
    const float* __restrict__ Wq, const float* __restrict__ bq, const float* __restrict__ Wkv,
    float* __restrict__ M_r, float* __restrict__ M_ea, float* __restrict__ br, float* __restrict__ bea) {
    int o = blockIdx.x * 256 + threadIdx.x;
    if (o < 2048) {
        int k = o >> 4, j = o & 15;
        float acc = 0.f;
        for (int d = 0; d < 128; ++d) acc += Wq[k * 128 + d] * Wkv[(size_t)j * 256 + 2 * d];
        M_r[k * 16 + j] = acc;
    } else if (o < 4096) {
        int k = (o - 2048) >> 4, j = o & 15;
        float acc = 0.f;
        for (int d = 0; d < 128; ++d) acc += Wq[k * 128 + d] * Wkv[(size_t)(144 + j) * 256 + 2 * d];
        M_ea[k * 16 + j] = acc;
    } else if (o < 4112) {
        int j = o - 4096;
        float acc = 0.f;
        for (int d = 0; d < 128; ++d) acc += bq[d] * Wkv[(size_t)j * 256 + 2 * d];
        br[j] = acc;
    } else if (o < 4128) {
        int j = o - 4112;
        float acc = 0.f;
        for (int d = 0; d < 128; ++d) acc += bq[d] * Wkv[(size_t)(144 + j) * 256 + 2 * d];
        bea[j] = acc;
    }
}

// ---------------------------------------------------------------- prepA: WA frag tables (split bf16)
// WA(128 x 416) cols: [Wq(128) | Wkv even (128) | Wkv odd (128) | M_r(16) | M_ea(16)]
__global__ __launch_bounds__(256) void k_prepA(
    const float* __restrict__ Wq, const float* __restrict__ Wkv,
    const float* __restrict__ M_r, const float* __restrict__ M_ea,
    u16* __restrict__ WAf_hi, u16* __restrict__ WAf_lo) {
    int idx = blockIdx.x * 256 + threadIdx.x;   // 26*4*64 = 6656
    if (idx >= 6656) return;
    int lane = idx & 63;
    int tkc = idx >> 6;
    int t = tkc >> 2, kc = tkc & 3;
    int col = t * 16 + (lane & 15);
    int k0 = kc * 32 + (lane >> 4) * 8;
#pragma unroll
    for (int j = 0; j < 8; ++j) {
        int k = k0 + j;
        float v;
        if (col < 128)      v = Wq[(size_t)k * 128 + col];
        else if (col < 256) v = Wkv[(size_t)(16 + k) * 256 + 2 * (col - 128)];
        else if (col < 384) v = Wkv[(size_t)(16 + k) * 256 + 2 * (col - 256) + 1];
        else if (col < 400) v = M_r[k * 16 + (col - 384)];
        else                v = M_ea[k * 16 + (col - 400)];
        u16 hi = f2bf(v);
        WAf_hi[(size_t)idx * 8 + j] = hi;
        WAf_lo[(size_t)idx * 8 + j] = f2bf(v - bf2f(hi));
    }
}

// ---------------------------------------------------------------- prepB: Wc1 frag tables (split bf16)
__global__ __launch_bounds__(256) void k_prepB(
    const float* __restrict__ Wc1, u16* __restrict__ Wc1f_hi, u16* __restrict__ Wc1f_lo) {
    int idx = blockIdx.x * 256 + threadIdx.x;   // 32*4*64 = 8192
    int lane = idx & 63;
    int tkc = idx >> 6;
    int t = tkc >> 2, kc = tkc & 3;
    int jc = t * 16 + (lane & 15);
    int k0 = kc * 32 + (lane >> 4) * 8;
#pragma unroll
    for (int j = 0; j < 8; ++j) {
        float v = Wc1[(size_t)(k0 + j) * 512 + jc];
        u16 hi = f2bf(v);
        Wc1f_hi[(size_t)idx * 8 + j] = hi;
        Wc1f_lo[(size_t)idx * 8 + j] = f2bf(v - bf2f(hi));
    }
}

// ---------------------------------------------------------------- GEMM A: [hq|k_h|v|hqWkr|hqWkea] = h @ WA (split-bf16 MFMA)
__global__ __launch_bounds__(256) void k_gemmA(
    const float* __restrict__ h, const u16* __restrict__ WAf_hi, const u16* __restrict__ WAf_lo,
    const float* __restrict__ bq, const float* __restrict__ bkv,
    const float* __restrict__ br, const float* __restrict__ bea,
    float* __restrict__ hq, float* __restrict__ k_h, u16* __restrict__ v_hi16, u16* __restrict__ v_lo16,
    float* __restrict__ hqWkr, float* __restrict__ hqWkea) {
    __shared__ __align__(16) u16 hhi[16][128];
    __shared__ __align__(16) u16 hlo[16][128];
    int t = threadIdx.x;
    int n0 = blockIdx.x * 16;
    for (int i = t; i < 2048; i += 256) {
        int n = i >> 7, d = i & 127;
        float x = h[(size_t)(n0 + n) * 128 + d];
        u16 hi = f2bf(x);
        hhi[n][d] = hi;
        hlo[n][d] = f2bf(x - bf2f(hi));
    }
    __syncthreads();
    int wv = t >> 6, lane = t & 63;
    int m = lane & 15, q = lane >> 4;
    short8 ahi[4], alo[4];
#pragma unroll
    for (int kc = 0; kc < 4; ++kc) {
        ahi[kc] = *(const short8*)(&hhi[m][kc * 32 + q * 8]);
        alo[kc] = *(const short8*)(&hlo[m][kc * 32 + q * 8]);
    }
    for (int tt = wv; tt < 26; tt += 4) {
        floatx4 acc = {0.f, 0.f, 0.f, 0.f};
#pragma unroll
        for (int kc = 0; kc < 4; ++kc) {
            size_t fo = ((size_t)(tt * 4 + kc) * 64 + lane) * 8;
            short8 bhi = *(const short8*)(WAf_hi + fo);
            short8 blo = *(const short8*)(WAf_lo + fo);
            acc = __builtin_amdgcn_mfma_f32_16x16x32_bf16(ahi[kc], bhi, acc, 0, 0, 0);
            acc = __builtin_amdgcn_mfma_f32_16x16x32_bf16(ahi[kc], blo, acc, 0, 0, 0);
            acc = __builtin_amdgcn_mfma_f32_16x16x32_bf16(alo[kc], bhi, acc, 0, 0, 0);
        }
        int col = tt * 16 + m;
        if (tt < 8) {
            float b = bq[col];
#pragma unroll
            for (int reg = 0; reg < 4; ++reg)
                hq[(size_t)(n0 + q * 4 + reg) * 128 + col] = acc[reg] + b;
        } else if (tt < 16) {
            int d = col - 128;
            float b = bkv[2 * d];
#pragma unroll
            for (int reg = 0; reg < 4; ++reg)
                k_h[(size_t)(n0 + q * 4 + reg) * 128 + d] = acc[reg] + b;
        } else if (tt < 24) {
            int d = col - 256;
            float b = bkv[2 * d + 1];
#pragma unroll
            for (int reg = 0; reg < 4; ++reg) {
                float vf = acc[reg] + b;
                u16 hi = f2bf(vf);
                size_t o = (size_t)(n0 + q * 4 + reg) * 128 + d;
                v_hi16[o] = hi;
                v_lo16[o] = f2bf(vf - bf2f(hi));
            }
        } else if (tt == 24) {
            float b = br[m];
#pragma unroll
            for (int reg = 0; reg < 4; ++reg)
                hqWkr[(size_t)(n0 + q * 4 + reg) * 16 + m] = acc[reg] + b;
        } else {
            float b = bea[m];
#pragma unroll
            for (int reg = 0; reg < 4; ++reg)
                hqWkea[(size_t)(n0 + q * 4 + reg) * 16 + m] = acc[reg] + b;
        }
    }
}

// ---------------------------------------------------------------- GEMM B: vWc1s = v @ Wc1 (split-bf16 MFMA)
// SWIZZLED output layout: vWc1s[n][(jc&15)*32 + (jc>>4)] so k_edge_z lane m reads contiguously
__global__ __launch_bounds__(256) void k_gemmB(
    const u16* __restrict__ v_hi16, const u16* __restrict__ v_lo16,
    const u16* __restrict__ Wc1f_hi, const u16* __restrict__ Wc1f_lo,
    u16* __restrict__ vWc1s) {
    int t = threadIdx.x;
    int n0 = blockIdx.x * 16;
    int wv = t >> 6, lane = t & 63;
    int m = lane & 15, q = lane >> 4;
    short8 ahi[4], alo[4];
#pragma unroll
    for (int kc = 0; kc < 4; ++kc) {
        size_t o = (size_t)(n0 + m) * 128 + kc * 32 + q * 8;
        ahi[kc] = *(const short8*)(v_hi16 + o);
        alo[kc] = *(const short8*)(v_lo16 + o);
    }
    for (int tt = wv; tt < 32; tt += 4) {
        floatx4 acc = {0.f, 0.f, 0.f, 0.f};
#pragma unroll
        for (int kc = 0; kc < 4; ++kc) {
            size_t fo = ((size_t)(tt * 4 + kc) * 64 + lane) * 8;
            short8 bhi = *(const short8*)(Wc1f_hi + fo);
            short8 blo = *(const short8*)(Wc1f_lo + fo);
            acc = __builtin_amdgcn_mfma_f32_16x16x32_bf16(ahi[kc], bhi, acc, 0, 0, 0);
            acc = __builtin_amdgcn_mfma_f32_16x16x32_bf16(ahi[kc], blo, acc, 0, 0, 0);
            acc = __builtin_amdgcn_mfma_f32_16x16x32_bf16(alo[kc], bhi, acc, 0, 0, 0);
        }
        // jc = tt*16 + m  ->  swizzled index m*32 + tt
#pragma unroll
        for (int reg = 0; reg < 4; ++reg)
            vWc1s[(size_t)(n0 + q * 4 + reg) * 512 + m * 32 + tt] = f2bf(acc[reg]);
    }
}

// ---------------------------------------------------------------- composites Cr/Cea (32 x 512)
__global__ __launch_bounds__(256) void k_composites(
    const float* __restrict__ Wkv, const float* __restrict__ Wc1,
    float* __restrict__ Cr, float* __restrict__ Cea) {
    int o = blockIdx.x * 256 + threadIdx.x;   // 16384 exact
    int half = o >> 13;
    int j = (o >> 9) & 15;
    int jc = o & 511;
    int row = half ? (144 + j) : j;
    float acc = 0.f;
    for (int d = 0; d < 128; ++d)
        acc += Wkv[(size_t)row * 256 + 2 * d + 1] * Wc1[(size_t)d * 512 + jc];
    (half ? Cea : Cr)[j * 512 + jc] = acc;
}

// ---------------------------------------------------------------- degree histogram (row + col)
__global__ __launch_bounds__(256) void k_hist_both(const int* __restrict__ edge_index,
                                                   int* __restrict__ countsR, int* __restrict__ countsC) {
    int i = blockIdx.x * 256 + threadIdx.x;
    if (i < E_) {
        atomicAdd(&countsR[edge_index[i]], 1);
        atomicAdd(&countsC[edge_index[E_ + i]], 1);
    }
}

// ---------------------------------------------------------------- dual exclusive scan (single block)
__global__ __launch_bounds__(1024) void k_scan2(
    const int* __restrict__ countsR, const int* __restrict__ countsC,
    int* __restrict__ offR, int* __restrict__ curR,
    int* __restrict__ offC, int* __restrict__ curC) {
    __shared__ int wtotR[16], wtotC[16];
    int t = threadIdx.x;
    int lane = t & 63, wv = t >> 6;
    int baseR = 0, baseC = 0;
    for (int start = 0; start < N_; start += 1024) {
        int i = start + t;
        int oR = (i < N_) ? countsR[i] : 0;
        int oC = (i < N_) ? countsC[i] : 0;
        int vR = oR, vC = oC;
#pragma unroll
        for (int off = 1; off < 64; off <<= 1) {
            int xR = __shfl_up(vR, off);
            int xC = __shfl_up(vC, off);
            if (lane >= off) { vR += xR; vC += xC; }
        }
        if (lane == 63) { wtotR[wv] = vR; wtotC[wv] = vC; }
        __syncthreads();
        int wbR = 0, totR = 0, wbC = 0, totC = 0;
#pragma unroll
        for (int k = 0; k < 16; ++k) {
            int wR = wtotR[k], wC = wtotC[k];
            if (k < wv) { wbR += wR; wbC += wC; }
            totR += wR; totC += wC;
        }
        if (i < N_) {
            int eR = baseR + wbR + vR - oR;
            int eC = baseC + wbC + vC - oC;
            offR[i] = eR; curR[i] = eR;
            offC[i] = eC; curC[i] = eC;
        }
        baseR += totR; baseC += totC;
        __syncthreads();
    }
    if (t == 0) { offR[N_] = baseR; offC[N_] = baseC; }
}

// ---------------------------------------------------------------- merged CSR fills (rank2 no longer needed)
__global__ void k_fill_both(const int* __restrict__ edge_index,
                            int* __restrict__ curR, int* __restrict__ curC,
                            int* __restrict__ edge_ids, int* __restrict__ edge_ids2) {
    int i = blockIdx.x * 256 + threadIdx.x;
    if (i < E_) {
        int r = edge_index[i], c = edge_index[E_ + i];
        int pr = atomicAdd(&curR[r], 1);
        edge_ids[pr] = i;
        int pc = atomicAdd(&curC[c], 1);
        edge_ids2[pc] = i;
    }
}

// ---------------------------------------------------------------- alpha in row-CSR order -> alpha_pos[p]
__global__ __launch_bounds__(256) void k_alpha_csr(
    const int* __restrict__ edge_index, const int* __restrict__ edge_ids,
    const float* __restrict__ coord, const float* __restrict__ edge_attr,
    const float* __restrict__ hq, const float* __restrict__ k_h,
    const float* __restrict__ hqWkr, const float* __restrict__ hqWkea,
    float* __restrict__ alpha_pos) {
    int wv = threadIdx.x >> 6, lane = threadIdx.x & 63;
    int p = blockIdx.x * 4 + wv;
    int e = edge_ids[p];
    int row = edge_index[e], col = edge_index[E_ + e];
    float s = hq[(size_t)row * 128 + lane] * k_h[(size_t)col * 128 + lane] +
              hq[(size_t)row * 128 + 64 + lane] * k_h[(size_t)col * 128 + 64 + lane];
    if (lane < 16) {
        int c = lane >> 2, f = lane & 3;
        float rj = 0.f;
#pragma unroll
        for (int x = 0; x < 3; ++x) {
            float a = coord[(size_t)row * 12 + c * 3 + x] - coord[(size_t)col * 12 + c * 3 + x];
            float b = coord[(size_t)row * 12 + f * 3 + x] - coord[(size_t)col * 12 + f * 3 + x];
            rj += a * b;
        }
        s += hqWkr[(size_t)row * 16 + lane] * rj;
    } else if (lane < 32) {
        int j = lane - 16;
        s += hqWkea[(size_t)row * 16 + j] * edge_attr[(size_t)e * 16 + j];
    }
#pragma unroll
    for (int mm = 32; mm; mm >>= 1) s += __shfl_xor(s, mm);
    if (lane == 0) alpha_pos[p] = s;
}

// ---------------------------------------------------------------- per-edge Z (col-CSR order), MFMA
// vWc1s swizzled: lane m's 32 per-tile values contiguous -> 4x dwordx4 per reg instead of 32 ushort loads
__global__ __launch_bounds__(256, 3) void k_edge_z(
    const int* __restrict__ edge_index, const int* __restrict__ edge_ids2,
    const float* __restrict__ coord, const float* __restrict__ edge_attr,
    const float* __restrict__ Cr, const float* __restrict__ Cea, const float* __restrict__ Wc2,
    const u16* __restrict__ vWc1s, float* __restrict__ Z) {
    __shared__ __align__(16) u16 Bf[32 * 64 * 8];   // 32 KB B-fragment table
    __shared__ __align__(16) float W2[512 * 4];     // 8 KB [jc][c]
    __shared__ __align__(16) u16 Xs[64][16];        // 2 KB radial staging
    int t = threadIdx.x;
    for (int i = t; i < 2048; i += 256) {
        int tile = i >> 6, ln = i & 63;
        int jc = tile * 16 + (ln & 15);
        int k0 = (ln >> 4) * 8;
#pragma unroll
        for (int j = 0; j < 8; ++j) {
            int k = k0 + j;
            float v = (k < 16) ? Cr[(size_t)k * 512 + jc] : Cea[(size_t)(k - 16) * 512 + jc];
            Bf[i * 8 + j] = f2bf(v);
        }
    }
    for (int i = t; i < 2048; i += 256) W2[i] = Wc2[i];
    __syncthreads();
    int wv = t >> 6, lane = t & 63;
    int m = lane & 15, q = lane >> 4;
    int wid = blockIdx.x * 4 + wv;
    int nw = gridDim.x * 4;
    for (int ti = wid; ti < E_ / 16; ti += nw) {
        int p0 = ti * 16;
#pragma unroll
        for (int i4 = 0; i4 < 4; ++i4) {
            int e = edge_ids2[p0 + i4 * 4 + q];
            int row = edge_index[e], col = edge_index[E_ + e];
            float d = 0.f;
            if (m < 12) d = coord[(size_t)row * 12 + m] - coord[(size_t)col * 12 + m];
            int base = lane & 48;
            int c3 = (m >> 2) * 3, f3 = (m & 3) * 3;
            float r = 0.f;
#pragma unroll
            for (int x = 0; x < 3; ++x) r += __shfl(d, base + c3 + x) * __shfl(d, base + f3 + x);
            Xs[wv * 16 + i4 * 4 + q][m] = f2bf(r);
        }
        short8 afrag;
        if (q < 2) {
            afrag = *(const short8*)(&Xs[wv * 16 + m][q * 8]);
        } else {
            int em = edge_ids2[p0 + m];
            const float* ea = edge_attr + (size_t)em * 16 + (q - 2) * 8;
#pragma unroll
            for (int j = 0; j < 8; ++j) afrag[j] = (short)f2bf(ea[j]);
        }
        int er[4], cr[4];
#pragma unroll
        for (int reg = 0; reg < 4; ++reg) {
            er[reg] = edge_ids2[p0 + q * 4 + reg];
            cr[reg] = edge_index[E_ + er[reg]];
        }
        float cvp[4][4];
#pragma unroll
        for (int reg = 0; reg < 4; ++reg)
#pragma unroll
            for (int c = 0; c < 4; ++c) cvp[reg][c] = 0.f;
        // 4 chunks of 8 tiles; per chunk: 4 vector loads of vWc1s (8 u16 each)
        for (int cc = 0; cc < 4; ++cc) {
            short8 vv[4];
#pragma unroll
            for (int reg = 0; reg < 4; ++reg)
                vv[reg] = *(const short8*)(vWc1s + (size_t)cr[reg] * 512 + m * 32 + cc * 8);
#pragma unroll
            for (int tj = 0; tj < 8; ++tj) {
                int tt = cc * 8 + tj;
                short8 bfrag = *(const short8*)(Bf + (size_t)(tt * 64 + lane) * 8);
                floatx4 acc = {0.f, 0.f, 0.f, 0.f};
                acc = __builtin_amdgcn_mfma_f32_16x16x32_bf16(afrag, bfrag, acc, 0, 0, 0);
                int jc = tt * 16 + m;
                float4 w2 = *(const float4*)(W2 + jc * 4);
#pragma unroll
                for (int reg = 0; reg < 4; ++reg) {
                    float u = acc[reg] + bf2f((u16)vv[reg][tj]);
                    float su = u / (1.f + __expf(-u));
                    cvp[reg][0] += su * w2.x;
                    cvp[reg][1] += su * w2.y;
                    cvp[reg][2] += su * w2.z;
                    cvp[reg][3] += su * w2.w;
                }
            }
        }
#pragma unroll
        for (int mm = 1; mm < 16; mm <<= 1)
#pragma unroll
            for (int reg = 0; reg < 4; ++reg)
#pragma unroll
                for (int c = 0; c < 4; ++c) cvp[reg][c] += __shfl_xor(cvp[reg][c], mm);
        if (m < 4) {
#pragma unroll
            for (int reg = 0; reg < 4; ++reg)
                Z[(size_t)er[reg] * 4 + m] = cvp[reg][m];   // indexed by edge id
        }
    }
}

// ---------------------------------------------------------------- per-node softmax + aggregations
__global__ __launch_bounds__(256) void k_node_main(
    const int* __restrict__ edge_index, const int* __restrict__ offsets, const int* __restrict__ edge_ids,
    const float* __restrict__ alpha_pos,
    const u16* __restrict__ v_h16, const float* __restrict__ Z,
    const float* __restrict__ coord, const float* __restrict__ edge_attr, const float* __restrict__ h,
    const float* __restrict__ Wkv, float* __restrict__ h_out, float* __restrict__ coord_out,
    float* __restrict__ att_out) {
    __shared__ float attL[4][128];
    int wv = threadIdx.x >> 6, lane = threadIdx.x & 63;
    int n = blockIdx.x * 4 + wv;
    int beg = offsets[n], end = offsets[n + 1];
    float cn[12];
#pragma unroll
    for (int i = 0; i < 12; ++i) cn[i] = coord[(size_t)n * 12 + i];
    // softmax max (dense alpha reads)
    float mloc = -3.402823466e38f;
    for (int i = beg + lane; i < end; i += 64) mloc = fmaxf(mloc, alpha_pos[i]);
#pragma unroll
    for (int mm = 32; mm; mm >>= 1) mloc = fmaxf(mloc, __shfl_xor(mloc, mm));
    // softmax sum
    float sloc = 0.f;
    for (int i = beg + lane; i < end; i += 64) sloc += __expf(alpha_pos[i] - mloc);
#pragma unroll
    for (int mm = 32; mm; mm >>= 1) sloc += __shfl_xor(sloc, mm);
    float inv_s = (end > beg) ? 1.f / sloc : 0.f;
    // lane-parallel pass (caches att in LDS for the serial pass)
    float raggr[16], eaggr[16], cagg[12];
#pragma unroll
    for (int j = 0; j < 16; ++j) { raggr[j] = 0.f; eaggr[j] = 0.f; }
#pragma unroll
    for (int j = 0; j < 12; ++j) cagg[j] = 0.f;
    for (int ii = lane; ii < end - beg; ii += 64) {
        int i = beg + ii;
        int e = edge_ids[i];
        int col = edge_index[E_ + e];
        float att = __expf(alpha_pos[i] - mloc) * inv_s;
        if (ii < 128) attL[wv][ii] = att;
        att_out[e] = att;
        float cd[12];
#pragma unroll
        for (int x = 0; x < 12; ++x) cd[x] = cn[x] - coord[(size_t)col * 12 + x];
#pragma unroll
        for (int c = 0; c < 4; ++c)
#pragma unroll
            for (int f = 0; f < 4; ++f) {
                float r = cd[c * 3] * cd[f * 3] + cd[c * 3 + 1] * cd[f * 3 + 1] + cd[c * 3 + 2] * cd[f * 3 + 2];
                raggr[c * 4 + f] += att * r;
            }
#pragma unroll
        for (int j = 0; j < 16; ++j) eaggr[j] += att * edge_attr[(size_t)e * 16 + j];
        size_t zb = (size_t)e * 4;
        float cv0 = att * Z[zb + 0];
        float cv1 = att * Z[zb + 1];
        float cv2 = att * Z[zb + 2];
        float cv3 = att * Z[zb + 3];
#pragma unroll
        for (int x = 0; x < 3; ++x) {
            cagg[0 + x] += cv0 * cd[0 + x];
            cagg[3 + x] += cv1 * cd[3 + x];
            cagg[6 + x] += cv2 * cd[6 + x];
            cagg[9 + x] += cv3 * cd[9 + x];
        }
    }
#pragma unroll
    for (int mm = 32; mm; mm >>= 1) {
#pragma unroll
        for (int j = 0; j < 16; ++j) {
            raggr[j] += __shfl_xor(raggr[j], mm);
            eaggr[j] += __shfl_xor(eaggr[j], mm);
        }
#pragma unroll
        for (int j = 0; j < 12; ++j) cagg[j] += __shfl_xor(cagg[j], mm);
    }
    // wave-cooperative agg (128-dim, bf16 v_h), att from LDS cache
    float agg0 = 0.f, agg1 = 0.f;
    int deg = end - beg;
    for (int i = 0; i < deg; ++i) {
        int e = edge_ids[beg + i];
        int col = edge_index[E_ + e];
        float att = (i < 128) ? attL[wv][i] : __expf(alpha_pos[beg + i] - mloc) * inv_s;
        agg0 += att * bf2f(v_h16[(size_t)col * 128 + lane]);
        agg1 += att * bf2f(v_h16[(size_t)col * 128 + 64 + lane]);
    }
#pragma unroll
    for (int g = 0; g < 2; ++g) {
        int dd = g * 64 + lane;
        float acc = g ? agg1 : agg0;
#pragma unroll
        for (int j = 0; j < 16; ++j) {
            acc += raggr[j] * Wkv[(size_t)j * 256 + 2 * dd + 1];
            acc += eaggr[j] * Wkv[(size_t)(144 + j) * 256 + 2 * dd + 1];
        }
        h_out[(size_t)n * 128 + dd] = h[(size_t)n * 128 + dd] + acc;
    }
    if (lane == 0) {
#pragma unroll
        for (int i = 0; i < 12; ++i) {
            float v = fminf(fmaxf(cagg[i], -10.f), 10.f);
            coord_out[(size_t)n * 12 + i] = cn[i] + v;
        }
    }
}

// ================================================================ SLOW (validated) FALLBACK PATH
__global__ __launch_bounds__(256) void k_hq_slow(
    const float* __restrict__ h, const float* __restrict__ Wq, const float* __restrict__ bq,
    float* __restrict__ hq) {
    int idx = blockIdx.x * 256 + threadIdx.x;
    int n = idx >> 7, d = idx & 127;
    float acc = 0.f;
    for (int k = 0; k < 128; ++k) acc += h[(size_t)n * 128 + k] * Wq[k * 128 + d];
    hq[idx] = acc + bq[d];
}

__global__ __launch_bounds__(256) void k_alpha_slow(
    const int* __restrict__ edge_index, const float* __restrict__ coord,
    const float* __restrict__ edge_attr, const float* __restrict__ h,
    const float* __restrict__ Wkv, const float* __restrict__ bkv,
    const float* __restrict__ hq, float* __restrict__ alpha, unsigned int* __restrict__ m) {
    __shared__ float tf[4][160];
    int wv = threadIdx.x >> 6, lane = threadIdx.x & 63;
    int e = blockIdx.x * 4 + wv;
    int row = edge_index[e], col = edge_index[E_ + e];
    if (lane < 16) {
        int c = lane >> 2, f = lane & 3;
        float rj = 0.f;
#pragma unroll
        for (int x = 0; x < 3; ++x) {
            float a = coord[(size_t)row * 12 + c * 3 + x] - coord[(size_t)col * 12 + c * 3 + x];
            float b = coord[(size_t)row * 12 + f * 3 + x] - coord[(size_t)col * 12 + f * 3 + x];
            rj += a * b;
        }
        tf[wv][lane] = rj;
    }
    for (int f = lane; f < 128; f += 64) tf[wv][16 + f] = h[(size_t)col * 128 + f];
    if (lane >= 48) tf[wv][144 + lane - 48] = edge_attr[(size_t)e * 16 + lane - 48];
    __syncthreads();
    float k0 = bkv[2 * lane], k1 = bkv[2 * (64 + lane)];
    for (int f = 0; f < 160; ++f) {
        float tfv = tf[wv][f];
        k0 += tfv * Wkv[f * 256 + 2 * lane];
        k1 += tfv * Wkv[f * 256 + 128 + 2 * lane];
    }
    float p = hq[(size_t)row * 128 + lane] * k0 + hq[(size_t)row * 128 + 64 + lane] * k1;
#pragma unroll
    for (int mm = 32; mm; mm >>= 1) p += __shfl_xor(p, mm);
    if (lane == 0) {
        alpha[e] = p;
        atomicMax(&m[row], fenc(p));
    }
}

__global__ __launch_bounds__(256) void k_expsum_slow(
    const int* __restrict__ edge_index, const float* __restrict__ alpha,
    const unsigned int* __restrict__ m, float* __restrict__ s) {
    int e = blockIdx.x * 256 + threadIdx.x;
    if (e < E_) {
        int row = edge_index[e];
        atomicAdd(&s[row], __expf(alpha[e] - fdec(m[row])));
    }
}

__global__ __launch_bounds__(256) void k_edge2_slow(
    const int* __restrict__ edge_index, const float* __restrict__ coord,
    const float* __restrict__ edge_attr, const float* __restrict__ h,
    const float* __restrict__ Wkv, const float* __restrict__ bkv,
    const float* __restrict__ Wc1, const float* __restrict__ Wc2,
    const float* __restrict__ alpha, const unsigned int* __restrict__ m, const float* __restrict__ s,
    float* __restrict__ agg, float* __restrict__ cagg, float* __restrict__ att_out) {
    __shared__ float tf[4][160];
    __shared__ float vsh[4][128];
    int wv = threadIdx.x >> 6, lane = threadIdx.x & 63;
    int e = blockIdx.x * 4 + wv;
    int row = edge_index[e], col = edge_index[E_ + e];
    if (lane < 16) {
        int c = lane >> 2, f = lane & 3;
        float rj = 0.f;
#pragma unroll
        for (int x = 0; x < 3; ++x) {
            float a = coord[(size_t)row * 12 + c * 3 + x] - coord[(size_t)col * 12 + c * 3 + x];
            float b = coord[(size_t)row * 12 + f * 3 + x] - coord[(size_t)col * 12 + f * 3 + x];
            rj += a * b;
        }
        tf[wv][lane] = rj;
    }
    for (int f = lane; f < 128; f += 64) tf[wv][16 + f] = h[(size_t)col * 128 + f];
    if (lane >= 48) tf[wv][144 + lane - 48] = edge_attr[(size_t)e * 16 + lane - 48];
    __syncthreads();
    float v0 = bkv[2 * lane + 1], v1 = bkv[2 * (64 + lane) + 1];
    for (int f = 0; f < 160; ++f) {
        float tfv = tf[wv][f];
        v0 += tfv * Wkv[f * 256 + 2 * lane + 1];
        v1 += tfv * Wkv[f * 256 + 129 + 2 * lane];
    }
    float att = __expf(alpha[e] - fdec(m[row])) / s[row];
    atomicAdd(&agg[(size_t)row * 128 + lane], att * v0);
    atomicAdd(&agg[(size_t)row * 128 + 64 + lane], att * v1);
    vsh[wv][lane] = v0;
    vsh[wv][64 + lane] = v1;
    __syncthreads();
    float cv[4] = {0.f, 0.f, 0.f, 0.f};
    for (int g = 0; g < 8; ++g) {
        int jc = g * 64 + lane;
        float u = 0.f;
        for (int dd = 0; dd < 128; ++dd) u += vsh[wv][dd] * Wc1[dd * 512 + jc];
        float su = u / (1.f + __expf(-u));
#pragma unroll
        for (int c = 0; c < 4; ++c) cv[c] += su * Wc2[jc * 4 + c];
    }
#pragma unroll
    for (int mm = 32; mm; mm >>= 1)
#pragma unroll
        for (int c = 0; c < 4; ++c) cv[c] += __shfl_xor(cv[c], mm);
    if (lane < 12) {
        int c = lane / 3;
        float cd = coord[(size_t)row * 12 + lane] - coord[(size_t)col * 12 + lane];
        atomicAdd(&cagg[(size_t)row * 12 + lane], att * cv[c] * cd);
    }
    if (lane == 0) att_out[e] = att;
}

__global__ __launch_bounds__(256) void k_final_slow(
    const float* __restrict__ h, const float* __restrict__ coord,
    const float* __restrict__ agg, const float* __restrict__ cagg,
    float* __restrict__ h_out, float* __restrict__ coord_out) {
    int idx = blockIdx.x * 256 + threadIdx.x;
    h_out[idx] = h[idx] + agg[idx];
    if (idx < N_ * 12) {
        float v = fminf(fmaxf(cagg[idx], -10.f), 10.f);
        coord_out[idx] = coord[idx] + v;
    }
}

// ---------------------------------------------------------------- launch
extern "C" void kernel_launch(void* const* d_in, const int* in_sizes, int n_in,
                              void* d_out, int out_size, void* d_ws, size_t ws_size,
                              hipStream_t stream) {
    (void)in_sizes; (void)n_in; (void)out_size;
    const float* h          = (const float*)d_in[0];
    const float* coord      = (const float*)d_in[1];
    const int*   edge_index = (const int*)d_in[2];
    const float* edge_attr  = (const float*)d_in[3];
    const float* Wq         = (const float*)d_in[4];
    const float* bq         = (const float*)d_in[5];
    const float* Wkv        = (const float*)d_in[6];
    const float* bkv        = (const float*)d_in[7];
    const float* Wc1        = (const float*)d_in[8];
    const float* Wc2        = (const float*)d_in[9];

    float* out = (float*)d_out;
    float* h_out = out;
    float* coord_out = out + (size_t)N_ * 128;
    float* att_out = coord_out + (size_t)N_ * 12;

    char* w = (char*)d_ws;
    size_t off = 0;
    auto alloc = [&](size_t bytes) -> void* {
        void* p = w + off;
        off += (bytes + 255) & ~(size_t)255;
        return p;
    };
    // ---- fast-path layout (counts as one contiguous 2N block — round-10 bug)
    int* countsR   = (int*)alloc((size_t)2 * N_ * 4);      // zeroed as a whole
    int* countsC   = countsR + N_;
    float* hq      = (float*)alloc((size_t)N_ * 128 * 4);
    float* k_h     = (float*)alloc((size_t)N_ * 128 * 4);
    u16*   v_h16   = (u16*)alloc((size_t)N_ * 128 * 2);    // = v_hi
    u16*   v_lo16  = (u16*)alloc((size_t)N_ * 128 * 2);
    u16*   vWc1s   = (u16*)alloc((size_t)N_ * 512 * 2);    // swizzled (jc&15)*32+(jc>>4)
    float* hqWkr   = (float*)alloc((size_t)N_ * 16 * 4);
    float* hqWkea  = (float*)alloc((size_t)N_ * 16 * 4);
    float* alphaP  = (float*)alloc((size_t)E_ * 4);        // by row-CSR position
    float* Z       = (float*)alloc((size_t)E_ * 4 * 4);    // by edge id
    float* Cr      = (float*)alloc(16 * 512 * 4);
    float* Cea     = (float*)alloc(16 * 512 * 4);
    float* M_r     = (float*)alloc(128 * 16 * 4);
    float* M_ea    = (float*)alloc(128 * 16 * 4);
    float* br      = (float*)alloc(16 * 4);
    float* bea     = (float*)alloc(16 * 4);
    u16* WAf_hi    = (u16*)alloc((size_t)26 * 4 * 64 * 8 * 2);
    u16* WAf_lo    = (u16*)alloc((size_t)26 * 4 * 64 * 8 * 2);
    u16* Wc1f_hi   = (u16*)alloc((size_t)32 * 4 * 64 * 8 * 2);
    u16* Wc1f_lo   = (u16*)alloc((size_t)32 * 4 * 64 * 8 * 2);
    int* offsetsR  = (int*)alloc((size_t)(N_ + 1) * 4);
    int* cursorR   = (int*)alloc((size_t)N_ * 4);
    int* edge_ids  = (int*)alloc((size_t)E_ * 4);
    int* offsetsC  = (int*)alloc((size_t)(N_ + 1) * 4);
    int* cursorC   = (int*)alloc((size_t)N_ * 4);
    int* edge_ids2 = (int*)alloc((size_t)E_ * 4);
    size_t fast_req = off;

    if (ws_size >= fast_req) {
        hipLaunchKernelGGL(k_zero, dim3((2 * N_ + 255) / 256), dim3(256), 0, stream,
                           (unsigned int*)countsR, 2 * N_);
        hipLaunchKernelGGL(k_hist_both, dim3((E_ + 255) / 256), dim3(256), 0, stream,
                           edge_index, countsR, countsC);
        hipLaunchKernelGGL(k_scan2, dim3(1), dim3(1024), 0, stream,
                           countsR, countsC, offsetsR, cursorR, offsetsC, cursorC);
        hipLaunchKernelGGL(k_fill_both, dim3((E_ + 255) / 256), dim3(256), 0, stream,
                           edge_index, cursorR, cursorC, edge_ids, edge_ids2);
        hipLaunchKernelGGL(k_prep0, dim3(17), dim3(256), 0, stream,
                           Wq, bq, Wkv, M_r, M_ea, br, bea);
        hipLaunchKernelGGL(k_prepA, dim3(26), dim3(256), 0, stream,
                           Wq, Wkv, M_r, M_ea, WAf_hi, WAf_lo);
        hipLaunchKernelGGL(k_prepB, dim3(32), dim3(256), 0, stream,
                           Wc1, Wc1f_hi, Wc1f_lo);
        hipLaunchKernelGGL(k_composites, dim3(64), dim3(256), 0, stream, Wkv, Wc1, Cr, Cea);
        hipLaunchKernelGGL(k_gemmA, dim3(N_ / 16), dim3(256), 0, stream,
                           h, WAf_hi, WAf_lo, bq, bkv, br, bea,
                           hq, k_h, v_h16, v_lo16, hqWkr, hqWkea);
        hipLaunchKernelGGL(k_gemmB, dim3(N_ / 16), dim3(256), 0, stream,
                           v_h16, v_lo16, Wc1f_hi, Wc1f_lo, vWc1s);
        hipLaunchKernelGGL(k_alpha_csr, dim3(E_ / 4), dim3(256), 0, stream,
                           edge_index, edge_ids, coord, edge_attr, hq, k_h, hqWkr, hqWkea, alphaP);
        hipLaunchKernelGGL(k_edge_z, dim3(768), dim3(256), 0, stream,
                           edge_index, edge_ids2, coord, edge_attr, Cr, Cea, Wc2, vWc1s, Z);
        hipLaunchKernelGGL(k_node_main, dim3(N_ / 4), dim3(256), 0, stream,
                           edge_index, offsetsR, edge_ids, alphaP, v_h16, Z,
                           coord, edge_attr, h, Wkv, h_out, coord_out, att_out);
    } else {
        // ---- slow validated path (separate layout from offset 0)
        off = 0;
        float* s        = (float*)alloc((size_t)N_ * 4);
        unsigned int* m = (unsigned int*)alloc((size_t)N_ * 4);
        float* agg      = (float*)alloc((size_t)N_ * 128 * 4);
        float* cagg     = (float*)alloc((size_t)N_ * 12 * 4);
        size_t zb       = off;
        float* hq2      = (float*)alloc((size_t)N_ * 128 * 4);
        float* alpha2   = (float*)alloc((size_t)E_ * 4);
        int zero_n = (int)(zb / 4);
        hipLaunchKernelGGL(k_zero, dim3((zero_n + 255) / 256), dim3(256), 0, stream,
                           (unsigned int*)s, zero_n);
        hipLaunchKernelGGL(k_hq_slow, dim3(N_ * 128 / 256), dim3(256), 0, stream, h, Wq, bq, hq2);
        hipLaunchKernelGGL(k_alpha_slow, dim3(E_ / 4), dim3(256), 0, stream,
                           edge_index, coord, edge_attr, h, Wkv, bkv, hq2, alpha2, m);
        hipLaunchKernelGGL(k_expsum_slow, dim3((E_ + 255) / 256), dim3(256), 0, stream,
                           edge_index, alpha2, m, s);
        hipLaunchKernelGGL(k_edge2_slow, dim3(E_ / 4), dim3(256), 0, stream,
                           edge_index, coord, edge_attr, h, Wkv, bkv, Wc1, Wc2,
                           alpha2, m, s, agg, cagg, att_out);
        hipLaunchKernelGGL(k_final_slow, dim3(N_ * 128 / 256), dim3(256), 0, stream,
                           h, coord, agg, cagg, h_out, coord_out);
    }
}

// Round 16
// 738.573 us; speedup vs baseline: 1.1147x; 1.1147x over previous
//
#include <hip/hip_runtime.h>

typedef unsigned short u16;
typedef __attribute__((ext_vector_type(8))) short short8;
typedef __attribute__((ext_vector_type(4))) float floatx4;

constexpr int N_ = 20000;
constexpr int E_ = 400000;

#define DEV __device__ __forceinline__

DEV float bf2f(u16 u) { union { unsigned int i; float f; } x; x.i = ((unsigned int)u) << 16; return x.f; }
DEV u16 f2bf(float f) {
    union { unsigned int i; float f; } x; x.f = f;
    unsigned int i = x.i;
    unsigned int r = i + 0x7FFFu + ((i >> 16) & 1u);
    return (u16)(r >> 16);
}
// order-preserving float<->uint for atomicMax (unsigned) [slow path only]
DEV unsigned int fenc(float f) {
    unsigned int i = __float_as_uint(f);
    return (i & 0x80000000u) ? ~i : (i | 0x80000000u);
}
DEV float fdec(unsigned int u) {
    return (u & 0x80000000u) ? __uint_as_float(u ^ 0x80000000u) : __uint_as_float(~u);
}

// ---------------------------------------------------------------- zero a uint span
__global__ __launch_bounds__(256) void k_zero(unsigned int* p, int n) {
    int i = blockIdx.x * 256 + threadIdx.x;
    if (i < n) p[i] = 0u;
}

// ================================================================ FAST PATH
// ---------------------------------------------------------------- prep0: composites M_r/M_ea + bias constants
__global__ __launch_bounds__(256) void k_prep0(
    const float* __restrict__ Wq, const float* __restrict__ bq, const float* __restrict__ Wkv,
    float* __restrict__ M_r, float* __restrict__ M_ea, float* __restrict__ br, float* __restrict__ bea) {
    int o = blockIdx.x * 256 + threadIdx.x;
    if (o < 2048) {
        int k = o >> 4, j = o & 15;
        float acc = 0.f;
        for (int d = 0; d < 128; ++d) acc += Wq[k * 128 + d] * Wkv[(size_t)j * 256 + 2 * d];
        M_r[k * 16 + j] = acc;
    } else if (o < 4096) {
        int k = (o - 2048) >> 4, j = o & 15;
        float acc = 0.f;
        for (int d = 0; d < 128; ++d) acc += Wq[k * 128 + d] * Wkv[(size_t)(144 + j) * 256 + 2 * d];
        M_ea[k * 16 + j] = acc;
    } else if (o < 4112) {
        int j = o - 4096;
        float acc = 0.f;
        for (int d = 0; d < 128; ++d) acc += bq[d] * Wkv[(size_t)j * 256 + 2 * d];
        br[j] = acc;
    } else if (o < 4128) {
        int j = o - 4112;
        float acc = 0.f;
        for (int d = 0; d < 128; ++d) acc += bq[d] * Wkv[(size_t)(144 + j) * 256 + 2 * d];
        bea[j] = acc;
    }
}

// ---------------------------------------------------------------- prepA: WA frag tables (split bf16)
__global__ __launch_bounds__(256) void k_prepA(
    const float* __restrict__ Wq, const float* __restrict__ Wkv,
    const float* __restrict__ M_r, const float* __restrict__ M_ea,
    u16* __restrict__ WAf_hi, u16* __restrict__ WAf_lo) {
    int idx = blockIdx.x * 256 + threadIdx.x;   // 26*4*64 = 6656
    if (idx >= 6656) return;
    int lane = idx & 63;
    int tkc = idx >> 6;
    int t = tkc >> 2, kc = tkc & 3;
    int col = t * 16 + (lane & 15);
    int k0 = kc * 32 + (lane >> 4) * 8;
#pragma unroll
    for (int j = 0; j < 8; ++j) {
        int k = k0 + j;
        float v;
        if (col < 128)      v = Wq[(size_t)k * 128 + col];
        else if (col < 256) v = Wkv[(size_t)(16 + k) * 256 + 2 * (col - 128)];
        else if (col < 384) v = Wkv[(size_t)(16 + k) * 256 + 2 * (col - 256) + 1];
        else if (col < 400) v = M_r[k * 16 + (col - 384)];
        else                v = M_ea[k * 16 + (col - 400)];
        u16 hi = f2bf(v);
        WAf_hi[(size_t)idx * 8 + j] = hi;
        WAf_lo[(size_t)idx * 8 + j] = f2bf(v - bf2f(hi));
    }
}

// ---------------------------------------------------------------- prepB: Wc1 frag tables (split bf16)
__global__ __launch_bounds__(256) void k_prepB(
    const float* __restrict__ Wc1, u16* __restrict__ Wc1f_hi, u16* __restrict__ Wc1f_lo) {
    int idx = blockIdx.x * 256 + threadIdx.x;   // 32*4*64 = 8192
    int lane = idx & 63;
    int tkc = idx >> 6;
    int t = tkc >> 2, kc = tkc & 3;
    int jc = t * 16 + (lane & 15);
    int k0 = kc * 32 + (lane >> 4) * 8;
#pragma unroll
    for (int j = 0; j < 8; ++j) {
        float v = Wc1[(size_t)(k0 + j) * 512 + jc];
        u16 hi = f2bf(v);
        Wc1f_hi[(size_t)idx * 8 + j] = hi;
        Wc1f_lo[(size_t)idx * 8 + j] = f2bf(v - bf2f(hi));
    }
}

// ---------------------------------------------------------------- GEMM A: [hq|k_h|v|hqWkr|hqWkea] = h @ WA (split-bf16 MFMA)
__global__ __launch_bounds__(256) void k_gemmA(
    const float* __restrict__ h, const u16* __restrict__ WAf_hi, const u16* __restrict__ WAf_lo,
    const float* __restrict__ bq, const float* __restrict__ bkv,
    const float* __restrict__ br, const float* __restrict__ bea,
    float* __restrict__ hq, float* __restrict__ k_h, u16* __restrict__ v_hi16, u16* __restrict__ v_lo16,
    float* __restrict__ hqWkr, float* __restrict__ hqWkea) {
    __shared__ __align__(16) u16 hhi[16][128];
    __shared__ __align__(16) u16 hlo[16][128];
    int t = threadIdx.x;
    int n0 = blockIdx.x * 16;
    for (int i = t; i < 2048; i += 256) {
        int n = i >> 7, d = i & 127;
        float x = h[(size_t)(n0 + n) * 128 + d];
        u16 hi = f2bf(x);
        hhi[n][d] = hi;
        hlo[n][d] = f2bf(x - bf2f(hi));
    }
    __syncthreads();
    int wv = t >> 6, lane = t & 63;
    int m = lane & 15, q = lane >> 4;
    short8 ahi[4], alo[4];
#pragma unroll
    for (int kc = 0; kc < 4; ++kc) {
        ahi[kc] = *(const short8*)(&hhi[m][kc * 32 + q * 8]);
        alo[kc] = *(const short8*)(&hlo[m][kc * 32 + q * 8]);
    }
    for (int tt = wv; tt < 26; tt += 4) {
        floatx4 acc = {0.f, 0.f, 0.f, 0.f};
#pragma unroll
        for (int kc = 0; kc < 4; ++kc) {
            size_t fo = ((size_t)(tt * 4 + kc) * 64 + lane) * 8;
            short8 bhi = *(const short8*)(WAf_hi + fo);
            short8 blo = *(const short8*)(WAf_lo + fo);
            acc = __builtin_amdgcn_mfma_f32_16x16x32_bf16(ahi[kc], bhi, acc, 0, 0, 0);
            acc = __builtin_amdgcn_mfma_f32_16x16x32_bf16(ahi[kc], blo, acc, 0, 0, 0);
            acc = __builtin_amdgcn_mfma_f32_16x16x32_bf16(alo[kc], bhi, acc, 0, 0, 0);
        }
        int col = tt * 16 + m;
        if (tt < 8) {
            float b = bq[col];
#pragma unroll
            for (int reg = 0; reg < 4; ++reg)
                hq[(size_t)(n0 + q * 4 + reg) * 128 + col] = acc[reg] + b;
        } else if (tt < 16) {
            int d = col - 128;
            float b = bkv[2 * d];
#pragma unroll
            for (int reg = 0; reg < 4; ++reg)
                k_h[(size_t)(n0 + q * 4 + reg) * 128 + d] = acc[reg] + b;
        } else if (tt < 24) {
            int d = col - 256;
            float b = bkv[2 * d + 1];
#pragma unroll
            for (int reg = 0; reg < 4; ++reg) {
                float vf = acc[reg] + b;
                u16 hi = f2bf(vf);
                size_t o = (size_t)(n0 + q * 4 + reg) * 128 + d;
                v_hi16[o] = hi;
                v_lo16[o] = f2bf(vf - bf2f(hi));
            }
        } else if (tt == 24) {
            float b = br[m];
#pragma unroll
            for (int reg = 0; reg < 4; ++reg)
                hqWkr[(size_t)(n0 + q * 4 + reg) * 16 + m] = acc[reg] + b;
        } else {
            float b = bea[m];
#pragma unroll
            for (int reg = 0; reg < 4; ++reg)
                hqWkea[(size_t)(n0 + q * 4 + reg) * 16 + m] = acc[reg] + b;
        }
    }
}

// ---------------------------------------------------------------- GEMM B: vWc1s = v @ Wc1 (split-bf16 MFMA)
// SWIZZLED output layout: vWc1s[n][(jc&15)*32 + (jc>>4)]
__global__ __launch_bounds__(256) void k_gemmB(
    const u16* __restrict__ v_hi16, const u16* __restrict__ v_lo16,
    const u16* __restrict__ Wc1f_hi, const u16* __restrict__ Wc1f_lo,
    u16* __restrict__ vWc1s) {
    int t = threadIdx.x;
    int n0 = blockIdx.x * 16;
    int wv = t >> 6, lane = t & 63;
    int m = lane & 15, q = lane >> 4;
    short8 ahi[4], alo[4];
#pragma unroll
    for (int kc = 0; kc < 4; ++kc) {
        size_t o = (size_t)(n0 + m) * 128 + kc * 32 + q * 8;
        ahi[kc] = *(const short8*)(v_hi16 + o);
        alo[kc] = *(const short8*)(v_lo16 + o);
    }
    for (int tt = wv; tt < 32; tt += 4) {
        floatx4 acc = {0.f, 0.f, 0.f, 0.f};
#pragma unroll
        for (int kc = 0; kc < 4; ++kc) {
            size_t fo = ((size_t)(tt * 4 + kc) * 64 + lane) * 8;
            short8 bhi = *(const short8*)(Wc1f_hi + fo);
            short8 blo = *(const short8*)(Wc1f_lo + fo);
            acc = __builtin_amdgcn_mfma_f32_16x16x32_bf16(ahi[kc], bhi, acc, 0, 0, 0);
            acc = __builtin_amdgcn_mfma_f32_16x16x32_bf16(ahi[kc], blo, acc, 0, 0, 0);
            acc = __builtin_amdgcn_mfma_f32_16x16x32_bf16(alo[kc], bhi, acc, 0, 0, 0);
        }
#pragma unroll
        for (int reg = 0; reg < 4; ++reg)
            vWc1s[(size_t)(n0 + q * 4 + reg) * 512 + m * 32 + tt] = f2bf(acc[reg]);
    }
}

// ---------------------------------------------------------------- composites Cr/Cea (32 x 512)
__global__ __launch_bounds__(256) void k_composites(
    const float* __restrict__ Wkv, const float* __restrict__ Wc1,
    float* __restrict__ Cr, float* __restrict__ Cea) {
    int o = blockIdx.x * 256 + threadIdx.x;   // 16384 exact
    int half = o >> 13;
    int j = (o >> 9) & 15;
    int jc = o & 511;
    int row = half ? (144 + j) : j;
    float acc = 0.f;
    for (int d = 0; d < 128; ++d)
        acc += Wkv[(size_t)row * 256 + 2 * d + 1] * Wc1[(size_t)d * 512 + jc];
    (half ? Cea : Cr)[j * 512 + jc] = acc;
}

// ---------------------------------------------------------------- degree histogram (row + col)
__global__ __launch_bounds__(256) void k_hist_both(const int* __restrict__ edge_index,
                                                   int* __restrict__ countsR, int* __restrict__ countsC) {
    int i = blockIdx.x * 256 + threadIdx.x;
    if (i < E_) {
        atomicAdd(&countsR[edge_index[i]], 1);
        atomicAdd(&countsC[edge_index[E_ + i]], 1);
    }
}

// ---------------------------------------------------------------- dual exclusive scan (single block)
__global__ __launch_bounds__(1024) void k_scan2(
    const int* __restrict__ countsR, const int* __restrict__ countsC,
    int* __restrict__ offR, int* __restrict__ curR,
    int* __restrict__ offC, int* __restrict__ curC) {
    __shared__ int wtotR[16], wtotC[16];
    int t = threadIdx.x;
    int lane = t & 63, wv = t >> 6;
    int baseR = 0, baseC = 0;
    for (int start = 0; start < N_; start += 1024) {
        int i = start + t;
        int oR = (i < N_) ? countsR[i] : 0;
        int oC = (i < N_) ? countsC[i] : 0;
        int vR = oR, vC = oC;
#pragma unroll
        for (int off = 1; off < 64; off <<= 1) {
            int xR = __shfl_up(vR, off);
            int xC = __shfl_up(vC, off);
            if (lane >= off) { vR += xR; vC += xC; }
        }
        if (lane == 63) { wtotR[wv] = vR; wtotC[wv] = vC; }
        __syncthreads();
        int wbR = 0, totR = 0, wbC = 0, totC = 0;
#pragma unroll
        for (int k = 0; k < 16; ++k) {
            int wR = wtotR[k], wC = wtotC[k];
            if (k < wv) { wbR += wR; wbC += wC; }
            totR += wR; totC += wC;
        }
        if (i < N_) {
            int eR = baseR + wbR + vR - oR;
            int eC = baseC + wbC + vC - oC;
            offR[i] = eR; curR[i] = eR;
            offC[i] = eC; curC[i] = eC;
        }
        baseR += totR; baseC += totC;
        __syncthreads();
    }
    if (t == 0) { offR[N_] = baseR; offC[N_] = baseC; }
}

// ---------------------------------------------------------------- merged CSR fills
__global__ void k_fill_both(const int* __restrict__ edge_index,
                            int* __restrict__ curR, int* __restrict__ curC,
                            int* __restrict__ edge_ids, int* __restrict__ edge_ids2) {
    int i = blockIdx.x * 256 + threadIdx.x;
    if (i < E_) {
        int r = edge_index[i], c = edge_index[E_ + i];
        int pr = atomicAdd(&curR[r], 1);
        edge_ids[pr] = i;
        int pc = atomicAdd(&curC[c], 1);
        edge_ids2[pc] = i;
    }
}

// ---------------------------------------------------------------- alpha in row-CSR order -> alpha_pos[p]
__global__ __launch_bounds__(256) void k_alpha_csr(
    const int* __restrict__ edge_index, const int* __restrict__ edge_ids,
    const float* __restrict__ coord, const float* __restrict__ edge_attr,
    const float* __restrict__ hq, const float* __restrict__ k_h,
    const float* __restrict__ hqWkr, const float* __restrict__ hqWkea,
    float* __restrict__ alpha_pos) {
    int wv = threadIdx.x >> 6, lane = threadIdx.x & 63;
    int p = blockIdx.x * 4 + wv;
    int e = edge_ids[p];
    int row = edge_index[e], col = edge_index[E_ + e];
    float s = hq[(size_t)row * 128 + lane] * k_h[(size_t)col * 128 + lane] +
              hq[(size_t)row * 128 + 64 + lane] * k_h[(size_t)col * 128 + 64 + lane];
    if (lane < 16) {
        int c = lane >> 2, f = lane & 3;
        float rj = 0.f;
#pragma unroll
        for (int x = 0; x < 3; ++x) {
            float a = coord[(size_t)row * 12 + c * 3 + x] - coord[(size_t)col * 12 + c * 3 + x];
            float b = coord[(size_t)row * 12 + f * 3 + x] - coord[(size_t)col * 12 + f * 3 + x];
            rj += a * b;
        }
        s += hqWkr[(size_t)row * 16 + lane] * rj;
    } else if (lane < 32) {
        int j = lane - 16;
        s += hqWkea[(size_t)row * 16 + j] * edge_attr[(size_t)e * 16 + j];
    }
#pragma unroll
    for (int mm = 32; mm; mm >>= 1) s += __shfl_xor(s, mm);
    if (lane == 0) alpha_pos[p] = s;
}

// ---------------------------------------------------------------- per-edge Z (col-CSR order), MFMA
__global__ __launch_bounds__(256, 3) void k_edge_z(
    const int* __restrict__ edge_index, const int* __restrict__ edge_ids2,
    const float* __restrict__ coord, const float* __restrict__ edge_attr,
    const float* __restrict__ Cr, const float* __restrict__ Cea, const float* __restrict__ Wc2,
    const u16* __restrict__ vWc1s, float* __restrict__ Z) {
    __shared__ __align__(16) u16 Bf[32 * 64 * 8];   // 32 KB B-fragment table
    __shared__ __align__(16) float W2[512 * 4];     // 8 KB [jc][c]
    __shared__ __align__(16) u16 Xs[64][16];        // 2 KB radial staging
    int t = threadIdx.x;
    for (int i = t; i < 2048; i += 256) {
        int tile = i >> 6, ln = i & 63;
        int jc = tile * 16 + (ln & 15);
        int k0 = (ln >> 4) * 8;
#pragma unroll
        for (int j = 0; j < 8; ++j) {
            int k = k0 + j;
            float v = (k < 16) ? Cr[(size_t)k * 512 + jc] : Cea[(size_t)(k - 16) * 512 + jc];
            Bf[i * 8 + j] = f2bf(v);
        }
    }
    for (int i = t; i < 2048; i += 256) W2[i] = Wc2[i];
    __syncthreads();
    int wv = t >> 6, lane = t & 63;
    int m = lane & 15, q = lane >> 4;
    int wid = blockIdx.x * 4 + wv;
    int nw = gridDim.x * 4;
    for (int ti = wid; ti < E_ / 16; ti += nw) {
        int p0 = ti * 16;
#pragma unroll
        for (int i4 = 0; i4 < 4; ++i4) {
            int e = edge_ids2[p0 + i4 * 4 + q];
            int row = edge_index[e], col = edge_index[E_ + e];
            float d = 0.f;
            if (m < 12) d = coord[(size_t)row * 12 + m] - coord[(size_t)col * 12 + m];
            int base = lane & 48;
            int c3 = (m >> 2) * 3, f3 = (m & 3) * 3;
            float r = 0.f;
#pragma unroll
            for (int x = 0; x < 3; ++x) r += __shfl(d, base + c3 + x) * __shfl(d, base + f3 + x);
            Xs[wv * 16 + i4 * 4 + q][m] = f2bf(r);
        }
        short8 afrag;
        if (q < 2) {
            afrag = *(const short8*)(&Xs[wv * 16 + m][q * 8]);
        } else {
            int em = edge_ids2[p0 + m];
            const float* ea = edge_attr + (size_t)em * 16 + (q - 2) * 8;
#pragma unroll
            for (int j = 0; j < 8; ++j) afrag[j] = (short)f2bf(ea[j]);
        }
        int er[4], cr[4];
#pragma unroll
        for (int reg = 0; reg < 4; ++reg) {
            er[reg] = edge_ids2[p0 + q * 4 + reg];
            cr[reg] = edge_index[E_ + er[reg]];
        }
        float cvp[4][4];
#pragma unroll
        for (int reg = 0; reg < 4; ++reg)
#pragma unroll
            for (int c = 0; c < 4; ++c) cvp[reg][c] = 0.f;
        for (int cc = 0; cc < 4; ++cc) {
            short8 vv[4];
#pragma unroll
            for (int reg = 0; reg < 4; ++reg)
                vv[reg] = *(const short8*)(vWc1s + (size_t)cr[reg] * 512 + m * 32 + cc * 8);
#pragma unroll
            for (int tj = 0; tj < 8; ++tj) {
                int tt = cc * 8 + tj;
                short8 bfrag = *(const short8*)(Bf + (size_t)(tt * 64 + lane) * 8);
                floatx4 acc = {0.f, 0.f, 0.f, 0.f};
                acc = __builtin_amdgcn_mfma_f32_16x16x32_bf16(afrag, bfrag, acc, 0, 0, 0);
                int jc = tt * 16 + m;
                float4 w2 = *(const float4*)(W2 + jc * 4);
#pragma unroll
                for (int reg = 0; reg < 4; ++reg) {
                    float u = acc[reg] + bf2f((u16)vv[reg][tj]);
                    float su = u / (1.f + __expf(-u));
                    cvp[reg][0] += su * w2.x;
                    cvp[reg][1] += su * w2.y;
                    cvp[reg][2] += su * w2.z;
                    cvp[reg][3] += su * w2.w;
                }
            }
        }
#pragma unroll
        for (int mm = 1; mm < 16; mm <<= 1)
#pragma unroll
            for (int reg = 0; reg < 4; ++reg)
#pragma unroll
                for (int c = 0; c < 4; ++c) cvp[reg][c] += __shfl_xor(cvp[reg][c], mm);
        if (m < 4) {
#pragma unroll
            for (int reg = 0; reg < 4; ++reg)
                Z[(size_t)er[reg] * 4 + m] = cvp[reg][m];   // indexed by edge id
        }
    }
}

// ---------------------------------------------------------------- per-node softmax + aggregations
// serial agg loop: col cached in LDS (1-level dep chain), dword v loads (d=2*lane,2*lane+1), 4x unroll
__global__ __launch_bounds__(256) void k_node_main(
    const int* __restrict__ edge_index, const int* __restrict__ offsets, const int* __restrict__ edge_ids,
    const float* __restrict__ alpha_pos,
    const u16* __restrict__ v_h16, const float* __restrict__ Z,
    const float* __restrict__ coord, const float* __restrict__ edge_attr, const float* __restrict__ h,
    const float* __restrict__ Wkv, float* __restrict__ h_out, float* __restrict__ coord_out,
    float* __restrict__ att_out) {
    __shared__ float attL[4][128];
    __shared__ int colL[4][128];
    int wv = threadIdx.x >> 6, lane = threadIdx.x & 63;
    int n = blockIdx.x * 4 + wv;
    int beg = offsets[n], end = offsets[n + 1];
    int deg = end - beg;
    float cn[12];
#pragma unroll
    for (int i = 0; i < 12; ++i) cn[i] = coord[(size_t)n * 12 + i];
    // softmax max (dense alpha reads)
    float mloc = -3.402823466e38f;
    for (int i = beg + lane; i < end; i += 64) mloc = fmaxf(mloc, alpha_pos[i]);
#pragma unroll
    for (int mm = 32; mm; mm >>= 1) mloc = fmaxf(mloc, __shfl_xor(mloc, mm));
    // softmax sum
    float sloc = 0.f;
    for (int i = beg + lane; i < end; i += 64) sloc += __expf(alpha_pos[i] - mloc);
#pragma unroll
    for (int mm = 32; mm; mm >>= 1) sloc += __shfl_xor(sloc, mm);
    float inv_s = (deg > 0) ? 1.f / sloc : 0.f;
    // lane-parallel pass (caches att+col in LDS for the serial pass)
    float raggr[16], eaggr[16], cagg[12];
#pragma unroll
    for (int j = 0; j < 16; ++j) { raggr[j] = 0.f; eaggr[j] = 0.f; }
#pragma unroll
    for (int j = 0; j < 12; ++j) cagg[j] = 0.f;
    for (int ii = lane; ii < deg; ii += 64) {
        int i = beg + ii;
        int e = edge_ids[i];
        int col = edge_index[E_ + e];
        float att = __expf(alpha_pos[i] - mloc) * inv_s;
        if (ii < 128) { attL[wv][ii] = att; colL[wv][ii] = col; }
        att_out[e] = att;
        float cd[12];
#pragma unroll
        for (int x = 0; x < 12; ++x) cd[x] = cn[x] - coord[(size_t)col * 12 + x];
#pragma unroll
        for (int c = 0; c < 4; ++c)
#pragma unroll
            for (int f = 0; f < 4; ++f) {
                float r = cd[c * 3] * cd[f * 3] + cd[c * 3 + 1] * cd[f * 3 + 1] + cd[c * 3 + 2] * cd[f * 3 + 2];
                raggr[c * 4 + f] += att * r;
            }
#pragma unroll
        for (int j = 0; j < 16; ++j) eaggr[j] += att * edge_attr[(size_t)e * 16 + j];
        size_t zb = (size_t)e * 4;
        float cv0 = att * Z[zb + 0];
        float cv1 = att * Z[zb + 1];
        float cv2 = att * Z[zb + 2];
        float cv3 = att * Z[zb + 3];
#pragma unroll
        for (int x = 0; x < 3; ++x) {
            cagg[0 + x] += cv0 * cd[0 + x];
            cagg[3 + x] += cv1 * cd[3 + x];
            cagg[6 + x] += cv2 * cd[6 + x];
            cagg[9 + x] += cv3 * cd[9 + x];
        }
    }
#pragma unroll
    for (int mm = 32; mm; mm >>= 1) {
#pragma unroll
        for (int j = 0; j < 16; ++j) {
            raggr[j] += __shfl_xor(raggr[j], mm);
            eaggr[j] += __shfl_xor(eaggr[j], mm);
        }
#pragma unroll
        for (int j = 0; j < 12; ++j) cagg[j] += __shfl_xor(cagg[j], mm);
    }
    // wave-cooperative agg: lane covers d = 2*lane, 2*lane+1 (one dword load/edge), 4x unroll
    float aggE = 0.f, aggO = 0.f;
    int nf = deg < 128 ? deg : 128;
    int i = 0;
    for (; i + 4 <= nf; i += 4) {
        float a0 = attL[wv][i],     a1 = attL[wv][i + 1];
        float a2 = attL[wv][i + 2], a3 = attL[wv][i + 3];
        int c0 = colL[wv][i],     c1 = colL[wv][i + 1];
        int c2 = colL[wv][i + 2], c3 = colL[wv][i + 3];
        unsigned int p0 = *(const unsigned int*)(v_h16 + (size_t)c0 * 128 + 2 * lane);
        unsigned int p1 = *(const unsigned int*)(v_h16 + (size_t)c1 * 128 + 2 * lane);
        unsigned int p2 = *(const unsigned int*)(v_h16 + (size_t)c2 * 128 + 2 * lane);
        unsigned int p3 = *(const unsigned int*)(v_h16 + (size_t)c3 * 128 + 2 * lane);
        aggE += a0 * bf2f((u16)(p0 & 0xFFFFu)) + a1 * bf2f((u16)(p1 & 0xFFFFu)) +
                a2 * bf2f((u16)(p2 & 0xFFFFu)) + a3 * bf2f((u16)(p3 & 0xFFFFu));
        aggO += a0 * bf2f((u16)(p0 >> 16)) + a1 * bf2f((u16)(p1 >> 16)) +
                a2 * bf2f((u16)(p2 >> 16)) + a3 * bf2f((u16)(p3 >> 16));
    }
    for (; i < nf; ++i) {
        float a = attL[wv][i];
        int c = colL[wv][i];
        unsigned int p = *(const unsigned int*)(v_h16 + (size_t)c * 128 + 2 * lane);
        aggE += a * bf2f((u16)(p & 0xFFFFu));
        aggO += a * bf2f((u16)(p >> 16));
    }
    for (i = 128; i < deg; ++i) {  // fallback (deg>128 never expected)
        int e = edge_ids[beg + i];
        int c = edge_index[E_ + e];
        float a = __expf(alpha_pos[beg + i] - mloc) * inv_s;
        unsigned int p = *(const unsigned int*)(v_h16 + (size_t)c * 128 + 2 * lane);
        aggE += a * bf2f((u16)(p & 0xFFFFu));
        aggO += a * bf2f((u16)(p >> 16));
    }
    // epilogue: h_out at dd = 2*lane, 2*lane+1 (float2 ops; Wkv via float4 .y/.w)
    {
        float acc0 = aggE, acc1 = aggO;
#pragma unroll
        for (int j = 0; j < 16; ++j) {
            float4 wr = *(const float4*)(Wkv + (size_t)j * 256 + 4 * lane);
            float4 we = *(const float4*)(Wkv + (size_t)(144 + j) * 256 + 4 * lane);
            acc0 += raggr[j] * wr.y + eaggr[j] * we.y;
            acc1 += raggr[j] * wr.w + eaggr[j] * we.w;
        }
        float2 hv = *(const float2*)(h + (size_t)n * 128 + 2 * lane);
        float2 o;
        o.x = hv.x + acc0;
        o.y = hv.y + acc1;
        *(float2*)(h_out + (size_t)n * 128 + 2 * lane) = o;
    }
    if (lane == 0) {
#pragma unroll
        for (int i2 = 0; i2 < 12; ++i2) {
            float v = fminf(fmaxf(cagg[i2], -10.f), 10.f);
            coord_out[(size_t)n * 12 + i2] = cn[i2] + v;
        }
    }
}

// ================================================================ SLOW (validated) FALLBACK PATH
__global__ __launch_bounds__(256) void k_hq_slow(
    const float* __restrict__ h, const float* __restrict__ Wq, const float* __restrict__ bq,
    float* __restrict__ hq) {
    int idx = blockIdx.x * 256 + threadIdx.x;
    int n = idx >> 7, d = idx & 127;
    float acc = 0.f;
    for (int k = 0; k < 128; ++k) acc += h[(size_t)n * 128 + k] * Wq[k * 128 + d];
    hq[idx] = acc + bq[d];
}

__global__ __launch_bounds__(256) void k_alpha_slow(
    const int* __restrict__ edge_index, const float* __restrict__ coord,
    const float* __restrict__ edge_attr, const float* __restrict__ h,
    const float* __restrict__ Wkv, const float* __restrict__ bkv,
    const float* __restrict__ hq, float* __restrict__ alpha, unsigned int* __restrict__ m) {
    __shared__ float tf[4][160];
    int wv = threadIdx.x >> 6, lane = threadIdx.x & 63;
    int e = blockIdx.x * 4 + wv;
    int row = edge_index[e], col = edge_index[E_ + e];
    if (lane < 16) {
        int c = lane >> 2, f = lane & 3;
        float rj = 0.f;
#pragma unroll
        for (int x = 0; x < 3; ++x) {
            float a = coord[(size_t)row * 12 + c * 3 + x] - coord[(size_t)col * 12 + c * 3 + x];
            float b = coord[(size_t)row * 12 + f * 3 + x] - coord[(size_t)col * 12 + f * 3 + x];
            rj += a * b;
        }
        tf[wv][lane] = rj;
    }
    for (int f = lane; f < 128; f += 64) tf[wv][16 + f] = h[(size_t)col * 128 + f];
    if (lane >= 48) tf[wv][144 + lane - 48] = edge_attr[(size_t)e * 16 + lane - 48];
    __syncthreads();
    float k0 = bkv[2 * lane], k1 = bkv[2 * (64 + lane)];
    for (int f = 0; f < 160; ++f) {
        float tfv = tf[wv][f];
        k0 += tfv * Wkv[f * 256 + 2 * lane];
        k1 += tfv * Wkv[f * 256 + 128 + 2 * lane];
    }
    float p = hq[(size_t)row * 128 + lane] * k0 + hq[(size_t)row * 128 + 64 + lane] * k1;
#pragma unroll
    for (int mm = 32; mm; mm >>= 1) p += __shfl_xor(p, mm);
    if (lane == 0) {
        alpha[e] = p;
        atomicMax(&m[row], fenc(p));
    }
}

__global__ __launch_bounds__(256) void k_expsum_slow(
    const int* __restrict__ edge_index, const float* __restrict__ alpha,
    const unsigned int* __restrict__ m, float* __restrict__ s) {
    int e = blockIdx.x * 256 + threadIdx.x;
    if (e < E_) {
        int row = edge_index[e];
        atomicAdd(&s[row], __expf(alpha[e] - fdec(m[row])));
    }
}

__global__ __launch_bounds__(256) void k_edge2_slow(
    const int* __restrict__ edge_index, const float* __restrict__ coord,
    const float* __restrict__ edge_attr, const float* __restrict__ h,
    const float* __restrict__ Wkv, const float* __restrict__ bkv,
    const float* __restrict__ Wc1, const float* __restrict__ Wc2,
    const float* __restrict__ alpha, const unsigned int* __restrict__ m, const float* __restrict__ s,
    float* __restrict__ agg, float* __restrict__ cagg, float* __restrict__ att_out) {
    __shared__ float tf[4][160];
    __shared__ float vsh[4][128];
    int wv = threadIdx.x >> 6, lane = threadIdx.x & 63;
    int e = blockIdx.x * 4 + wv;
    int row = edge_index[e], col = edge_index[E_ + e];
    if (lane < 16) {
        int c = lane >> 2, f = lane & 3;
        float rj = 0.f;
#pragma unroll
        for (int x = 0; x < 3; ++x) {
            float a = coord[(size_t)row * 12 + c * 3 + x] - coord[(size_t)col * 12 + c * 3 + x];
            float b = coord[(size_t)row * 12 + f * 3 + x] - coord[(size_t)col * 12 + f * 3 + x];
            rj += a * b;
        }
        tf[wv][lane] = rj;
    }
    for (int f = lane; f < 128; f += 64) tf[wv][16 + f] = h[(size_t)col * 128 + f];
    if (lane >= 48) tf[wv][144 + lane - 48] = edge_attr[(size_t)e * 16 + lane - 48];
    __syncthreads();
    float v0 = bkv[2 * lane + 1], v1 = bkv[2 * (64 + lane) + 1];
    for (int f = 0; f < 160; ++f) {
        float tfv = tf[wv][f];
        v0 += tfv * Wkv[f * 256 + 2 * lane + 1];
        v1 += tfv * Wkv[f * 256 + 129 + 2 * lane];
    }
    float att = __expf(alpha[e] - fdec(m[row])) / s[row];
    atomicAdd(&agg[(size_t)row * 128 + lane], att * v0);
    atomicAdd(&agg[(size_t)row * 128 + 64 + lane], att * v1);
    vsh[wv][lane] = v0;
    vsh[wv][64 + lane] = v1;
    __syncthreads();
    float cv[4] = {0.f, 0.f, 0.f, 0.f};
    for (int g = 0; g < 8; ++g) {
        int jc = g * 64 + lane;
        float u = 0.f;
        for (int dd = 0; dd < 128; ++dd) u += vsh[wv][dd] * Wc1[dd * 512 + jc];
        float su = u / (1.f + __expf(-u));
#pragma unroll
        for (int c = 0; c < 4; ++c) cv[c] += su * Wc2[jc * 4 + c];
    }
#pragma unroll
    for (int mm = 32; mm; mm >>= 1)
#pragma unroll
        for (int c = 0; c < 4; ++c) cv[c] += __shfl_xor(cv[c], mm);
    if (lane < 12) {
        int c = lane / 3;
        float cd = coord[(size_t)row * 12 + lane] - coord[(size_t)col * 12 + lane];
        atomicAdd(&cagg[(size_t)row * 12 + lane], att * cv[c] * cd);
    }
    if (lane == 0) att_out[e] = att;
}

__global__ __launch_bounds__(256) void k_final_slow(
    const float* __restrict__ h, const float* __restrict__ coord,
    const float* __restrict__ agg, const float* __restrict__ cagg,
    float* __restrict__ h_out, float* __restrict__ coord_out) {
    int idx = blockIdx.x * 256 + threadIdx.x;
    h_out[idx] = h[idx] + agg[idx];
    if (idx < N_ * 12) {
        float v = fminf(fmaxf(cagg[idx], -10.f), 10.f);
        coord_out[idx] = coord[idx] + v;
    }
}

// ---------------------------------------------------------------- launch
extern "C" void kernel_launch(void* const* d_in, const int* in_sizes, int n_in,
                              void* d_out, int out_size, void* d_ws, size_t ws_size,
                              hipStream_t stream) {
    (void)in_sizes; (void)n_in; (void)out_size;
    const float* h          = (const float*)d_in[0];
    const float* coord      = (const float*)d_in[1];
    const int*   edge_index = (const int*)d_in[2];
    const float* edge_attr  = (const float*)d_in[3];
    const float* Wq         = (const float*)d_in[4];
    const float* bq         = (const float*)d_in[5];
    const float* Wkv        = (const float*)d_in[6];
    const float* bkv        = (const float*)d_in[7];
    const float* Wc1        = (const float*)d_in[8];
    const float* Wc2        = (const float*)d_in[9];

    float* out = (float*)d_out;
    float* h_out = out;
    float* coord_out = out + (size_t)N_ * 128;
    float* att_out = coord_out + (size_t)N_ * 12;

    char* w = (char*)d_ws;
    size_t off = 0;
    auto alloc = [&](size_t bytes) -> void* {
        void* p = w + off;
        off += (bytes + 255) & ~(size_t)255;
        return p;
    };
    // ---- fast-path layout (counts as one contiguous 2N block — round-10 bug)
    int* countsR   = (int*)alloc((size_t)2 * N_ * 4);      // zeroed as a whole
    int* countsC   = countsR + N_;
    float* hq      = (float*)alloc((size_t)N_ * 128 * 4);
    float* k_h     = (float*)alloc((size_t)N_ * 128 * 4);
    u16*   v_h16   = (u16*)alloc((size_t)N_ * 128 * 2);    // = v_hi
    u16*   v_lo16  = (u16*)alloc((size_t)N_ * 128 * 2);
    u16*   vWc1s   = (u16*)alloc((size_t)N_ * 512 * 2);    // swizzled (jc&15)*32+(jc>>4)
    float* hqWkr   = (float*)alloc((size_t)N_ * 16 * 4);
    float* hqWkea  = (float*)alloc((size_t)N_ * 16 * 4);
    float* alphaP  = (float*)alloc((size_t)E_ * 4);        // by row-CSR position
    float* Z       = (float*)alloc((size_t)E_ * 4 * 4);    // by edge id
    float* Cr      = (float*)alloc(16 * 512 * 4);
    float* Cea     = (float*)alloc(16 * 512 * 4);
    float* M_r     = (float*)alloc(128 * 16 * 4);
    float* M_ea    = (float*)alloc(128 * 16 * 4);
    float* br      = (float*)alloc(16 * 4);
    float* bea     = (float*)alloc(16 * 4);
    u16* WAf_hi    = (u16*)alloc((size_t)26 * 4 * 64 * 8 * 2);
    u16* WAf_lo    = (u16*)alloc((size_t)26 * 4 * 64 * 8 * 2);
    u16* Wc1f_hi   = (u16*)alloc((size_t)32 * 4 * 64 * 8 * 2);
    u16* Wc1f_lo   = (u16*)alloc((size_t)32 * 4 * 64 * 8 * 2);
    int* offsetsR  = (int*)alloc((size_t)(N_ + 1) * 4);
    int* cursorR   = (int*)alloc((size_t)N_ * 4);
    int* edge_ids  = (int*)alloc((size_t)E_ * 4);
    int* offsetsC  = (int*)alloc((size_t)(N_ + 1) * 4);
    int* cursorC   = (int*)alloc((size_t)N_ * 4);
    int* edge_ids2 = (int*)alloc((size_t)E_ * 4);
    size_t fast_req = off;

    if (ws_size >= fast_req) {
        hipLaunchKernelGGL(k_zero, dim3((2 * N_ + 255) / 256), dim3(256), 0, stream,
                           (unsigned int*)countsR, 2 * N_);
        hipLaunchKernelGGL(k_hist_both, dim3((E_ + 255) / 256), dim3(256), 0, stream,
                           edge_index, countsR, countsC);
        hipLaunchKernelGGL(k_scan2, dim3(1), dim3(1024), 0, stream,
                           countsR, countsC, offsetsR, cursorR, offsetsC, cursorC);
        hipLaunchKernelGGL(k_fill_both, dim3((E_ + 255) / 256), dim3(256), 0, stream,
                           edge_index, cursorR, cursorC, edge_ids, edge_ids2);
        hipLaunchKernelGGL(k_prep0, dim3(17), dim3(256), 0, stream,
                           Wq, bq, Wkv, M_r, M_ea, br, bea);
        hipLaunchKernelGGL(k_prepA, dim3(26), dim3(256), 0, stream,
                           Wq, Wkv, M_r, M_ea, WAf_hi, WAf_lo);
        hipLaunchKernelGGL(k_prepB, dim3(32), dim3(256), 0, stream,
                           Wc1, Wc1f_hi, Wc1f_lo);
        hipLaunchKernelGGL(k_composites, dim3(64), dim3(256), 0, stream, Wkv, Wc1, Cr, Cea);
        hipLaunchKernelGGL(k_gemmA, dim3(N_ / 16), dim3(256), 0, stream,
                           h, WAf_hi, WAf_lo, bq, bkv, br, bea,
                           hq, k_h, v_h16, v_lo16, hqWkr, hqWkea);
        hipLaunchKernelGGL(k_gemmB, dim3(N_ / 16), dim3(256), 0, stream,
                           v_h16, v_lo16, Wc1f_hi, Wc1f_lo, vWc1s);
        hipLaunchKernelGGL(k_alpha_csr, dim3(E_ / 4), dim3(256), 0, stream,
                           edge_index, edge_ids, coord, edge_attr, hq, k_h, hqWkr, hqWkea, alphaP);
        hipLaunchKernelGGL(k_edge_z, dim3(768), dim3(256), 0, stream,
                           edge_index, edge_ids2, coord, edge_attr, Cr, Cea, Wc2, vWc1s, Z);
        hipLaunchKernelGGL(k_node_main, dim3(N_ / 4), dim3(256), 0, stream,
                           edge_index, offsetsR, edge_ids, alphaP, v_h16, Z,
                           coord, edge_attr, h, Wkv, h_out, coord_out, att_out);
    } else {
        // ---- slow validated path (separate layout from offset 0)
        off = 0;
        float* s        = (float*)alloc((size_t)N_ * 4);
        unsigned int* m = (unsigned int*)alloc((size_t)N_ * 4);
        float* agg      = (float*)alloc((size_t)N_ * 128 * 4);
        float* cagg     = (float*)alloc((size_t)N_ * 12 * 4);
        size_t zb       = off;
        float* hq2      = (float*)alloc((size_t)N_ * 128 * 4);
        float* alpha2   = (float*)alloc((size_t)E_ * 4);
        int zero_n = (int)(zb / 4);
        hipLaunchKernelGGL(k_zero, dim3((zero_n + 255) / 256), dim3(256), 0, stream,
                           (unsigned int*)s, zero_n);
        hipLaunchKernelGGL(k_hq_slow, dim3(N_ * 128 / 256), dim3(256), 0, stream, h, Wq, bq, hq2);
        hipLaunchKernelGGL(k_alpha_slow, dim3(E_ / 4), dim3(256), 0, stream,
                           edge_index, coord, edge_attr, h, Wkv, bkv, hq2, alpha2, m);
        hipLaunchKernelGGL(k_expsum_slow, dim3((E_ + 255) / 256), dim3(256), 0, stream,
                           edge_index, alpha2, m, s);
        hipLaunchKernelGGL(k_edge2_slow, dim3(E_ / 4), dim3(256), 0, stream,
                           edge_index, coord, edge_attr, h, Wkv, bkv, Wc1, Wc2,
                           alpha2, m, s, agg, cagg, att_out);
        hipLaunchKernelGGL(k_final_slow, dim3(N_ * 128 / 256), dim3(256), 0, stream,
                           h, coord, agg, cagg, h_out, coord_out);
    }
}

// Round 17
// 710.182 us; speedup vs baseline: 1.1593x; 1.0400x over previous
//
#include <hip/hip_runtime.h>

typedef unsigned short u16;
typedef __attribute__((ext_vector_type(8))) short short8;
typedef __attribute__((ext_vector_type(4))) float floatx4;

constexpr int N_ = 20000;
constexpr int E_ = 400000;

#define DEV __device__ __forceinline__

DEV float bf2f(u16 u) { union { unsigned int i; float f; } x; x.i = ((unsigned int)u) << 16; return x.f; }
DEV u16 f2bf(float f) {
    union { unsigned int i; float f; } x; x.f = f;
    unsigned int i = x.i;
    unsigned int r = i + 0x7FFFu + ((i >> 16) & 1u);
    return (u16)(r >> 16);
}
// order-preserving float<->uint for atomicMax (unsigned) [slow path only]
DEV unsigned int fenc(float f) {
    unsigned int i = __float_as_uint(f);
    return (i & 0x80000000u) ? ~i : (i | 0x80000000u);
}
DEV float fdec(unsigned int u) {
    return (u & 0x80000000u) ? __uint_as_float(u ^ 0x80000000u) : __uint_as_float(~u);
}

// ---------------------------------------------------------------- zero a uint span
__global__ __launch_bounds__(256) void k_zero(unsigned int* p, int n) {
    int i = blockIdx.x * 256 + threadIdx.x;
    if (i < n) p[i] = 0u;
}

// ================================================================ FAST PATH
// ---------------------------------------------------------------- prep0: composites M_r/M_ea + bias constants
__global__ __launch_bounds__(256) void k_prep0(
    const float* __restrict__ Wq, const float* __restrict__ bq, const float* __restrict__ Wkv,
    float* __restrict__ M_r, float* __restrict__ M_ea, float* __restrict__ br, float* __restrict__ bea) {
    int o = blockIdx.x * 256 + threadIdx.x;
    if (o < 2048) {
        int k = o >> 4, j = o & 15;
        float acc = 0.f;
        for (int d = 0; d < 128; ++d) acc += Wq[k * 128 + d] * Wkv[(size_t)j * 256 + 2 * d];
        M_r[k * 16 + j] = acc;
    } else if (o < 4096) {
        int k = (o - 2048) >> 4, j = o & 15;
        float acc = 0.f;
        for (int d = 0; d < 128; ++d) acc += Wq[k * 128 + d] * Wkv[(size_t)(144 + j) * 256 + 2 * d];
        M_ea[k * 16 + j] = acc;
    } else if (o < 4112) {
        int j = o - 4096;
        float acc = 0.f;
        for (int d = 0; d < 128; ++d) acc += bq[d] * Wkv[(size_t)j * 256 + 2 * d];
        br[j] = acc;
    } else if (o < 4128) {
        int j = o - 4112;
        float acc = 0.f;
        for (int d = 0; d < 128; ++d) acc += bq[d] * Wkv[(size_t)(144 + j) * 256 + 2 * d];
        bea[j] = acc;
    }
}

// ---------------------------------------------------------------- prepA: WA frag tables (split bf16)
__global__ __launch_bounds__(256) void k_prepA(
    const float* __restrict__ Wq, const float* __restrict__ Wkv,
    const float* __restrict__ M_r, const float* __restrict__ M_ea,
    u16* __restrict__ WAf_hi, u16* __restrict__ WAf_lo) {
    int idx = blockIdx.x * 256 + threadIdx.x;   // 26*4*64 = 6656
    if (idx >= 6656) return;
    int lane = idx & 63;
    int tkc = idx >> 6;
    int t = tkc >> 2, kc = tkc & 3;
    int col = t * 16 + (lane & 15);
    int k0 = kc * 32 + (lane >> 4) * 8;
#pragma unroll
    for (int j = 0; j < 8; ++j) {
        int k = k0 + j;
        float v;
        if (col < 128)      v = Wq[(size_t)k * 128 + col];
        else if (col < 256) v = Wkv[(size_t)(16 + k) * 256 + 2 * (col - 128)];
        else if (col < 384) v = Wkv[(size_t)(16 + k) * 256 + 2 * (col - 256) + 1];
        else if (col < 400) v = M_r[k * 16 + (col - 384)];
        else                v = M_ea[k * 16 + (col - 400)];
        u16 hi = f2bf(v);
        WAf_hi[(size_t)idx * 8 + j] = hi;
        WAf_lo[(size_t)idx * 8 + j] = f2bf(v - bf2f(hi));
    }
}

// ---------------------------------------------------------------- prepB: Wc1 frag tables (split bf16)
__global__ __launch_bounds__(256) void k_prepB(
    const float* __restrict__ Wc1, u16* __restrict__ Wc1f_hi, u16* __restrict__ Wc1f_lo) {
    int idx = blockIdx.x * 256 + threadIdx.x;   // 32*4*64 = 8192
    int lane = idx & 63;
    int tkc = idx >> 6;
    int t = tkc >> 2, kc = tkc & 3;
    int jc = t * 16 + (lane & 15);
    int k0 = kc * 32 + (lane >> 4) * 8;
#pragma unroll
    for (int j = 0; j < 8; ++j) {
        float v = Wc1[(size_t)(k0 + j) * 512 + jc];
        u16 hi = f2bf(v);
        Wc1f_hi[(size_t)idx * 8 + j] = hi;
        Wc1f_lo[(size_t)idx * 8 + j] = f2bf(v - bf2f(hi));
    }
}

// ---------------------------------------------------------------- GEMM A: [hq|k_h|v|hqWkr|hqWkea] = h @ WA (split-bf16 MFMA)
__global__ __launch_bounds__(256) void k_gemmA(
    const float* __restrict__ h, const u16* __restrict__ WAf_hi, const u16* __restrict__ WAf_lo,
    const float* __restrict__ bq, const float* __restrict__ bkv,
    const float* __restrict__ br, const float* __restrict__ bea,
    float* __restrict__ hq, float* __restrict__ k_h, u16* __restrict__ v_hi16, u16* __restrict__ v_lo16,
    float* __restrict__ hqWkr, float* __restrict__ hqWkea) {
    __shared__ __align__(16) u16 hhi[16][128];
    __shared__ __align__(16) u16 hlo[16][128];
    int t = threadIdx.x;
    int n0 = blockIdx.x * 16;
    for (int i = t; i < 2048; i += 256) {
        int n = i >> 7, d = i & 127;
        float x = h[(size_t)(n0 + n) * 128 + d];
        u16 hi = f2bf(x);
        hhi[n][d] = hi;
        hlo[n][d] = f2bf(x - bf2f(hi));
    }
    __syncthreads();
    int wv = t >> 6, lane = t & 63;
    int m = lane & 15, q = lane >> 4;
    short8 ahi[4], alo[4];
#pragma unroll
    for (int kc = 0; kc < 4; ++kc) {
        ahi[kc] = *(const short8*)(&hhi[m][kc * 32 + q * 8]);
        alo[kc] = *(const short8*)(&hlo[m][kc * 32 + q * 8]);
    }
    for (int tt = wv; tt < 26; tt += 4) {
        floatx4 acc = {0.f, 0.f, 0.f, 0.f};
#pragma unroll
        for (int kc = 0; kc < 4; ++kc) {
            size_t fo = ((size_t)(tt * 4 + kc) * 64 + lane) * 8;
            short8 bhi = *(const short8*)(WAf_hi + fo);
            short8 blo = *(const short8*)(WAf_lo + fo);
            acc = __builtin_amdgcn_mfma_f32_16x16x32_bf16(ahi[kc], bhi, acc, 0, 0, 0);
            acc = __builtin_amdgcn_mfma_f32_16x16x32_bf16(ahi[kc], blo, acc, 0, 0, 0);
            acc = __builtin_amdgcn_mfma_f32_16x16x32_bf16(alo[kc], bhi, acc, 0, 0, 0);
        }
        int col = tt * 16 + m;
        if (tt < 8) {
            float b = bq[col];
#pragma unroll
            for (int reg = 0; reg < 4; ++reg)
                hq[(size_t)(n0 + q * 4 + reg) * 128 + col] = acc[reg] + b;
        } else if (tt < 16) {
            int d = col - 128;
            float b = bkv[2 * d];
#pragma unroll
            for (int reg = 0; reg < 4; ++reg)
                k_h[(size_t)(n0 + q * 4 + reg) * 128 + d] = acc[reg] + b;
        } else if (tt < 24) {
            int d = col - 256;
            float b = bkv[2 * d + 1];
#pragma unroll
            for (int reg = 0; reg < 4; ++reg) {
                float vf = acc[reg] + b;
                u16 hi = f2bf(vf);
                size_t o = (size_t)(n0 + q * 4 + reg) * 128 + d;
                v_hi16[o] = hi;
                v_lo16[o] = f2bf(vf - bf2f(hi));
            }
        } else if (tt == 24) {
            float b = br[m];
#pragma unroll
            for (int reg = 0; reg < 4; ++reg)
                hqWkr[(size_t)(n0 + q * 4 + reg) * 16 + m] = acc[reg] + b;
        } else {
            float b = bea[m];
#pragma unroll
            for (int reg = 0; reg < 4; ++reg)
                hqWkea[(size_t)(n0 + q * 4 + reg) * 16 + m] = acc[reg] + b;
        }
    }
}

// ---------------------------------------------------------------- GEMM B: vWc1s = v @ Wc1 (split-bf16 MFMA)
// SWIZZLED output layout: vWc1s[n][(jc&15)*32 + (jc>>4)]
__global__ __launch_bounds__(256) void k_gemmB(
    const u16* __restrict__ v_hi16, const u16* __restrict__ v_lo16,
    const u16* __restrict__ Wc1f_hi, const u16* __restrict__ Wc1f_lo,
    u16* __restrict__ vWc1s) {
    int t = threadIdx.x;
    int n0 = blockIdx.x * 16;
    int wv = t >> 6, lane = t & 63;
    int m = lane & 15, q = lane >> 4;
    short8 ahi[4], alo[4];
#pragma unroll
    for (int kc = 0; kc < 4; ++kc) {
        size_t o = (size_t)(n0 + m) * 128 + kc * 32 + q * 8;
        ahi[kc] = *(const short8*)(v_hi16 + o);
        alo[kc] = *(const short8*)(v_lo16 + o);
    }
    for (int tt = wv; tt < 32; tt += 4) {
        floatx4 acc = {0.f, 0.f, 0.f, 0.f};
#pragma unroll
        for (int kc = 0; kc < 4; ++kc) {
            size_t fo = ((size_t)(tt * 4 + kc) * 64 + lane) * 8;
            short8 bhi = *(const short8*)(Wc1f_hi + fo);
            short8 blo = *(const short8*)(Wc1f_lo + fo);
            acc = __builtin_amdgcn_mfma_f32_16x16x32_bf16(ahi[kc], bhi, acc, 0, 0, 0);
            acc = __builtin_amdgcn_mfma_f32_16x16x32_bf16(ahi[kc], blo, acc, 0, 0, 0);
            acc = __builtin_amdgcn_mfma_f32_16x16x32_bf16(alo[kc], bhi, acc, 0, 0, 0);
        }
#pragma unroll
        for (int reg = 0; reg < 4; ++reg)
            vWc1s[(size_t)(n0 + q * 4 + reg) * 512 + m * 32 + tt] = f2bf(acc[reg]);
    }
}

// ---------------------------------------------------------------- composites Cr/Cea (32 x 512)
__global__ __launch_bounds__(256) void k_composites(
    const float* __restrict__ Wkv, const float* __restrict__ Wc1,
    float* __restrict__ Cr, float* __restrict__ Cea) {
    int o = blockIdx.x * 256 + threadIdx.x;   // 16384 exact
    int half = o >> 13;
    int j = (o >> 9) & 15;
    int jc = o & 511;
    int row = half ? (144 + j) : j;
    float acc = 0.f;
    for (int d = 0; d < 128; ++d)
        acc += Wkv[(size_t)row * 256 + 2 * d + 1] * Wc1[(size_t)d * 512 + jc];
    (half ? Cea : Cr)[j * 512 + jc] = acc;
}

// ---------------------------------------------------------------- degree histogram (row + col)
__global__ __launch_bounds__(256) void k_hist_both(const int* __restrict__ edge_index,
                                                   int* __restrict__ countsR, int* __restrict__ countsC) {
    int i = blockIdx.x * 256 + threadIdx.x;
    if (i < E_) {
        atomicAdd(&countsR[edge_index[i]], 1);
        atomicAdd(&countsC[edge_index[E_ + i]], 1);
    }
}

// ---------------------------------------------------------------- dual exclusive scan (single block)
__global__ __launch_bounds__(1024) void k_scan2(
    const int* __restrict__ countsR, const int* __restrict__ countsC,
    int* __restrict__ offR, int* __restrict__ curR,
    int* __restrict__ offC, int* __restrict__ curC) {
    __shared__ int wtotR[16], wtotC[16];
    int t = threadIdx.x;
    int lane = t & 63, wv = t >> 6;
    int baseR = 0, baseC = 0;
    for (int start = 0; start < N_; start += 1024) {
        int i = start + t;
        int oR = (i < N_) ? countsR[i] : 0;
        int oC = (i < N_) ? countsC[i] : 0;
        int vR = oR, vC = oC;
#pragma unroll
        for (int off = 1; off < 64; off <<= 1) {
            int xR = __shfl_up(vR, off);
            int xC = __shfl_up(vC, off);
            if (lane >= off) { vR += xR; vC += xC; }
        }
        if (lane == 63) { wtotR[wv] = vR; wtotC[wv] = vC; }
        __syncthreads();
        int wbR = 0, totR = 0, wbC = 0, totC = 0;
#pragma unroll
        for (int k = 0; k < 16; ++k) {
            int wR = wtotR[k], wC = wtotC[k];
            if (k < wv) { wbR += wR; wbC += wC; }
            totR += wR; totC += wC;
        }
        if (i < N_) {
            int eR = baseR + wbR + vR - oR;
            int eC = baseC + wbC + vC - oC;
            offR[i] = eR; curR[i] = eR;
            offC[i] = eC; curC[i] = eC;
        }
        baseR += totR; baseC += totC;
        __syncthreads();
    }
    if (t == 0) { offR[N_] = baseR; offC[N_] = baseC; }
}

// ---------------------------------------------------------------- merged CSR fills
__global__ void k_fill_both(const int* __restrict__ edge_index,
                            int* __restrict__ curR, int* __restrict__ curC,
                            int* __restrict__ edge_ids, int* __restrict__ edge_ids2) {
    int i = blockIdx.x * 256 + threadIdx.x;
    if (i < E_) {
        int r = edge_index[i], c = edge_index[E_ + i];
        int pr = atomicAdd(&curR[r], 1);
        edge_ids[pr] = i;
        int pc = atomicAdd(&curC[c], 1);
        edge_ids2[pc] = i;
    }
}

// ---------------------------------------------------------------- alpha in row-CSR order -> alpha_pos[p]
__global__ __launch_bounds__(256) void k_alpha_csr(
    const int* __restrict__ edge_index, const int* __restrict__ edge_ids,
    const float* __restrict__ coord, const float* __restrict__ edge_attr,
    const float* __restrict__ hq, const float* __restrict__ k_h,
    const float* __restrict__ hqWkr, const float* __restrict__ hqWkea,
    float* __restrict__ alpha_pos) {
    int wv = threadIdx.x >> 6, lane = threadIdx.x & 63;
    int p = blockIdx.x * 4 + wv;
    int e = edge_ids[p];
    int row = edge_index[e], col = edge_index[E_ + e];
    float s = hq[(size_t)row * 128 + lane] * k_h[(size_t)col * 128 + lane] +
              hq[(size_t)row * 128 + 64 + lane] * k_h[(size_t)col * 128 + 64 + lane];
    if (lane < 16) {
        int c = lane >> 2, f = lane & 3;
        float rj = 0.f;
#pragma unroll
        for (int x = 0; x < 3; ++x) {
            float a = coord[(size_t)row * 12 + c * 3 + x] - coord[(size_t)col * 12 + c * 3 + x];
            float b = coord[(size_t)row * 12 + f * 3 + x] - coord[(size_t)col * 12 + f * 3 + x];
            rj += a * b;
        }
        s += hqWkr[(size_t)row * 16 + lane] * rj;
    } else if (lane < 32) {
        int j = lane - 16;
        s += hqWkea[(size_t)row * 16 + j] * edge_attr[(size_t)e * 16 + j];
    }
#pragma unroll
    for (int mm = 32; mm; mm >>= 1) s += __shfl_xor(s, mm);
    if (lane == 0) alpha_pos[p] = s;
}

// ---------------------------------------------------------------- per-edge Z (col-CSR order), MFMA
// W2 read direct from global (L1-resident); silu via v_rcp; 4 blocks/CU
__global__ __launch_bounds__(256, 4) void k_edge_z(
    const int* __restrict__ edge_index, const int* __restrict__ edge_ids2,
    const float* __restrict__ coord, const float* __restrict__ edge_attr,
    const float* __restrict__ Cr, const float* __restrict__ Cea, const float* __restrict__ Wc2,
    const u16* __restrict__ vWc1s, float* __restrict__ Z) {
    __shared__ __align__(16) u16 Bf[32 * 64 * 8];   // 32 KB B-fragment table
    __shared__ __align__(16) u16 Xs[64][16];        // 2 KB radial staging
    int t = threadIdx.x;
    for (int i = t; i < 2048; i += 256) {
        int tile = i >> 6, ln = i & 63;
        int jc = tile * 16 + (ln & 15);
        int k0 = (ln >> 4) * 8;
#pragma unroll
        for (int j = 0; j < 8; ++j) {
            int k = k0 + j;
            float v = (k < 16) ? Cr[(size_t)k * 512 + jc] : Cea[(size_t)(k - 16) * 512 + jc];
            Bf[i * 8 + j] = f2bf(v);
        }
    }
    __syncthreads();
    int wv = t >> 6, lane = t & 63;
    int m = lane & 15, q = lane >> 4;
    int wid = blockIdx.x * 4 + wv;
    int nw = gridDim.x * 4;
    for (int ti = wid; ti < E_ / 16; ti += nw) {
        int p0 = ti * 16;
#pragma unroll
        for (int i4 = 0; i4 < 4; ++i4) {
            int e = edge_ids2[p0 + i4 * 4 + q];
            int row = edge_index[e], col = edge_index[E_ + e];
            float d = 0.f;
            if (m < 12) d = coord[(size_t)row * 12 + m] - coord[(size_t)col * 12 + m];
            int base = lane & 48;
            int c3 = (m >> 2) * 3, f3 = (m & 3) * 3;
            float r = 0.f;
#pragma unroll
            for (int x = 0; x < 3; ++x) r += __shfl(d, base + c3 + x) * __shfl(d, base + f3 + x);
            Xs[wv * 16 + i4 * 4 + q][m] = f2bf(r);
        }
        short8 afrag;
        if (q < 2) {
            afrag = *(const short8*)(&Xs[wv * 16 + m][q * 8]);
        } else {
            int em = edge_ids2[p0 + m];
            const float* ea = edge_attr + (size_t)em * 16 + (q - 2) * 8;
#pragma unroll
            for (int j = 0; j < 8; ++j) afrag[j] = (short)f2bf(ea[j]);
        }
        int er[4], cr[4];
#pragma unroll
        for (int reg = 0; reg < 4; ++reg) {
            er[reg] = edge_ids2[p0 + q * 4 + reg];
            cr[reg] = edge_index[E_ + er[reg]];
        }
        float cvp[4][4];
#pragma unroll
        for (int reg = 0; reg < 4; ++reg)
#pragma unroll
            for (int c = 0; c < 4; ++c) cvp[reg][c] = 0.f;
        for (int cc = 0; cc < 4; ++cc) {
            short8 vv[4];
#pragma unroll
            for (int reg = 0; reg < 4; ++reg)
                vv[reg] = *(const short8*)(vWc1s + (size_t)cr[reg] * 512 + m * 32 + cc * 8);
#pragma unroll
            for (int tj = 0; tj < 8; ++tj) {
                int tt = cc * 8 + tj;
                short8 bfrag = *(const short8*)(Bf + (size_t)(tt * 64 + lane) * 8);
                floatx4 acc = {0.f, 0.f, 0.f, 0.f};
                acc = __builtin_amdgcn_mfma_f32_16x16x32_bf16(afrag, bfrag, acc, 0, 0, 0);
                int jc = tt * 16 + m;
                float4 w2 = *(const float4*)(Wc2 + (size_t)jc * 4);
#pragma unroll
                for (int reg = 0; reg < 4; ++reg) {
                    float u = acc[reg] + bf2f((u16)vv[reg][tj]);
                    float su = u * __builtin_amdgcn_rcpf(1.f + __expf(-u));
                    cvp[reg][0] += su * w2.x;
                    cvp[reg][1] += su * w2.y;
                    cvp[reg][2] += su * w2.z;
                    cvp[reg][3] += su * w2.w;
                }
            }
        }
#pragma unroll
        for (int mm = 1; mm < 16; mm <<= 1)
#pragma unroll
            for (int reg = 0; reg < 4; ++reg)
#pragma unroll
                for (int c = 0; c < 4; ++c) cvp[reg][c] += __shfl_xor(cvp[reg][c], mm);
        if (m < 4) {
#pragma unroll
            for (int reg = 0; reg < 4; ++reg)
                Z[(size_t)er[reg] * 4 + m] = cvp[reg][m];   // indexed by edge id
        }
    }
}

// ---------------------------------------------------------------- per-node softmax + aggregations
__global__ __launch_bounds__(256) void k_node_main(
    const int* __restrict__ edge_index, const int* __restrict__ offsets, const int* __restrict__ edge_ids,
    const float* __restrict__ alpha_pos,
    const u16* __restrict__ v_h16, const float* __restrict__ Z,
    const float* __restrict__ coord, const float* __restrict__ edge_attr, const float* __restrict__ h,
    const float* __restrict__ Wkv, float* __restrict__ h_out, float* __restrict__ coord_out,
    float* __restrict__ att_out) {
    __shared__ float attL[4][128];
    __shared__ int colL[4][128];
    int wv = threadIdx.x >> 6, lane = threadIdx.x & 63;
    int n = blockIdx.x * 4 + wv;
    int beg = offsets[n], end = offsets[n + 1];
    int deg = end - beg;
    float cn[12];
#pragma unroll
    for (int i = 0; i < 12; ++i) cn[i] = coord[(size_t)n * 12 + i];
    float mloc = -3.402823466e38f;
    for (int i = beg + lane; i < end; i += 64) mloc = fmaxf(mloc, alpha_pos[i]);
#pragma unroll
    for (int mm = 32; mm; mm >>= 1) mloc = fmaxf(mloc, __shfl_xor(mloc, mm));
    float sloc = 0.f;
    for (int i = beg + lane; i < end; i += 64) sloc += __expf(alpha_pos[i] - mloc);
#pragma unroll
    for (int mm = 32; mm; mm >>= 1) sloc += __shfl_xor(sloc, mm);
    float inv_s = (deg > 0) ? 1.f / sloc : 0.f;
    float raggr[16], eaggr[16], cagg[12];
#pragma unroll
    for (int j = 0; j < 16; ++j) { raggr[j] = 0.f; eaggr[j] = 0.f; }
#pragma unroll
    for (int j = 0; j < 12; ++j) cagg[j] = 0.f;
    for (int ii = lane; ii < deg; ii += 64) {
        int i = beg + ii;
        int e = edge_ids[i];
        int col = edge_index[E_ + e];
        float att = __expf(alpha_pos[i] - mloc) * inv_s;
        if (ii < 128) { attL[wv][ii] = att; colL[wv][ii] = col; }
        att_out[e] = att;
        float cd[12];
#pragma unroll
        for (int x = 0; x < 12; ++x) cd[x] = cn[x] - coord[(size_t)col * 12 + x];
#pragma unroll
        for (int c = 0; c < 4; ++c)
#pragma unroll
            for (int f = 0; f < 4; ++f) {
                float r = cd[c * 3] * cd[f * 3] + cd[c * 3 + 1] * cd[f * 3 + 1] + cd[c * 3 + 2] * cd[f * 3 + 2];
                raggr[c * 4 + f] += att * r;
            }
#pragma unroll
        for (int j = 0; j < 16; ++j) eaggr[j] += att * edge_attr[(size_t)e * 16 + j];
        size_t zb = (size_t)e * 4;
        float cv0 = att * Z[zb + 0];
        float cv1 = att * Z[zb + 1];
        float cv2 = att * Z[zb + 2];
        float cv3 = att * Z[zb + 3];
#pragma unroll
        for (int x = 0; x < 3; ++x) {
            cagg[0 + x] += cv0 * cd[0 + x];
            cagg[3 + x] += cv1 * cd[3 + x];
            cagg[6 + x] += cv2 * cd[6 + x];
            cagg[9 + x] += cv3 * cd[9 + x];
        }
    }
#pragma unroll
    for (int mm = 32; mm; mm >>= 1) {
#pragma unroll
        for (int j = 0; j < 16; ++j) {
            raggr[j] += __shfl_xor(raggr[j], mm);
            eaggr[j] += __shfl_xor(eaggr[j], mm);
        }
#pragma unroll
        for (int j = 0; j < 12; ++j) cagg[j] += __shfl_xor(cagg[j], mm);
    }
    // wave-cooperative agg: lane covers d = 2*lane, 2*lane+1 (one dword load/edge), 4x unroll
    float aggE = 0.f, aggO = 0.f;
    int nf = deg < 128 ? deg : 128;
    int i = 0;
    for (; i + 4 <= nf; i += 4) {
        float a0 = attL[wv][i],     a1 = attL[wv][i + 1];
        float a2 = attL[wv][i + 2], a3 = attL[wv][i + 3];
        int c0 = colL[wv][i],     c1 = colL[wv][i + 1];
        int c2 = colL[wv][i + 2], c3 = colL[wv][i + 3];
        unsigned int p0 = *(const unsigned int*)(v_h16 + (size_t)c0 * 128 + 2 * lane);
        unsigned int p1 = *(const unsigned int*)(v_h16 + (size_t)c1 * 128 + 2 * lane);
        unsigned int p2 = *(const unsigned int*)(v_h16 + (size_t)c2 * 128 + 2 * lane);
        unsigned int p3 = *(const unsigned int*)(v_h16 + (size_t)c3 * 128 + 2 * lane);
        aggE += a0 * bf2f((u16)(p0 & 0xFFFFu)) + a1 * bf2f((u16)(p1 & 0xFFFFu)) +
                a2 * bf2f((u16)(p2 & 0xFFFFu)) + a3 * bf2f((u16)(p3 & 0xFFFFu));
        aggO += a0 * bf2f((u16)(p0 >> 16)) + a1 * bf2f((u16)(p1 >> 16)) +
                a2 * bf2f((u16)(p2 >> 16)) + a3 * bf2f((u16)(p3 >> 16));
    }
    for (; i < nf; ++i) {
        float a = attL[wv][i];
        int c = colL[wv][i];
        unsigned int p = *(const unsigned int*)(v_h16 + (size_t)c * 128 + 2 * lane);
        aggE += a * bf2f((u16)(p & 0xFFFFu));
        aggO += a * bf2f((u16)(p >> 16));
    }
    for (i = 128; i < deg; ++i) {  // fallback (deg>128 never expected)
        int e = edge_ids[beg + i];
        int c = edge_index[E_ + e];
        float a = __expf(alpha_pos[beg + i] - mloc) * inv_s;
        unsigned int p = *(const unsigned int*)(v_h16 + (size_t)c * 128 + 2 * lane);
        aggE += a * bf2f((u16)(p & 0xFFFFu));
        aggO += a * bf2f((u16)(p >> 16));
    }
    {
        float acc0 = aggE, acc1 = aggO;
#pragma unroll
        for (int j = 0; j < 16; ++j) {
            float4 wr = *(const float4*)(Wkv + (size_t)j * 256 + 4 * lane);
            float4 we = *(const float4*)(Wkv + (size_t)(144 + j) * 256 + 4 * lane);
            acc0 += raggr[j] * wr.y + eaggr[j] * we.y;
            acc1 += raggr[j] * wr.w + eaggr[j] * we.w;
        }
        float2 hv = *(const float2*)(h + (size_t)n * 128 + 2 * lane);
        float2 o;
        o.x = hv.x + acc0;
        o.y = hv.y + acc1;
        *(float2*)(h_out + (size_t)n * 128 + 2 * lane) = o;
    }
    if (lane == 0) {
#pragma unroll
        for (int i2 = 0; i2 < 12; ++i2) {
            float v = fminf(fmaxf(cagg[i2], -10.f), 10.f);
            coord_out[(size_t)n * 12 + i2] = cn[i2] + v;
        }
    }
}

// ================================================================ SLOW (validated) FALLBACK PATH
__global__ __launch_bounds__(256) void k_hq_slow(
    const float* __restrict__ h, const float* __restrict__ Wq, const float* __restrict__ bq,
    float* __restrict__ hq) {
    int idx = blockIdx.x * 256 + threadIdx.x;
    int n = idx >> 7, d = idx & 127;
    float acc = 0.f;
    for (int k = 0; k < 128; ++k) acc += h[(size_t)n * 128 + k] * Wq[k * 128 + d];
    hq[idx] = acc + bq[d];
}

__global__ __launch_bounds__(256) void k_alpha_slow(
    const int* __restrict__ edge_index, const float* __restrict__ coord,
    const float* __restrict__ edge_attr, const float* __restrict__ h,
    const float* __restrict__ Wkv, const float* __restrict__ bkv,
    const float* __restrict__ hq, float* __restrict__ alpha, unsigned int* __restrict__ m) {
    __shared__ float tf[4][160];
    int wv = threadIdx.x >> 6, lane = threadIdx.x & 63;
    int e = blockIdx.x * 4 + wv;
    int row = edge_index[e], col = edge_index[E_ + e];
    if (lane < 16) {
        int c = lane >> 2, f = lane & 3;
        float rj = 0.f;
#pragma unroll
        for (int x = 0; x < 3; ++x) {
            float a = coord[(size_t)row * 12 + c * 3 + x] - coord[(size_t)col * 12 + c * 3 + x];
            float b = coord[(size_t)row * 12 + f * 3 + x] - coord[(size_t)col * 12 + f * 3 + x];
            rj += a * b;
        }
        tf[wv][lane] = rj;
    }
    for (int f = lane; f < 128; f += 64) tf[wv][16 + f] = h[(size_t)col * 128 + f];
    if (lane >= 48) tf[wv][144 + lane - 48] = edge_attr[(size_t)e * 16 + lane - 48];
    __syncthreads();
    float k0 = bkv[2 * lane], k1 = bkv[2 * (64 + lane)];
    for (int f = 0; f < 160; ++f) {
        float tfv = tf[wv][f];
        k0 += tfv * Wkv[f * 256 + 2 * lane];
        k1 += tfv * Wkv[f * 256 + 128 + 2 * lane];
    }
    float p = hq[(size_t)row * 128 + lane] * k0 + hq[(size_t)row * 128 + 64 + lane] * k1;
#pragma unroll
    for (int mm = 32; mm; mm >>= 1) p += __shfl_xor(p, mm);
    if (lane == 0) {
        alpha[e] = p;
        atomicMax(&m[row], fenc(p));
    }
}

__global__ __launch_bounds__(256) void k_expsum_slow(
    const int* __restrict__ edge_index, const float* __restrict__ alpha,
    const unsigned int* __restrict__ m, float* __restrict__ s) {
    int e = blockIdx.x * 256 + threadIdx.x;
    if (e < E_) {
        int row = edge_index[e];
        atomicAdd(&s[row], __expf(alpha[e] - fdec(m[row])));
    }
}

__global__ __launch_bounds__(256) void k_edge2_slow(
    const int* __restrict__ edge_index, const float* __restrict__ coord,
    const float* __restrict__ edge_attr, const float* __restrict__ h,
    const float* __restrict__ Wkv, const float* __restrict__ bkv,
    const float* __restrict__ Wc1, const float* __restrict__ Wc2,
    const float* __restrict__ alpha, const unsigned int* __restrict__ m, const float* __restrict__ s,
    float* __restrict__ agg, float* __restrict__ cagg, float* __restrict__ att_out) {
    __shared__ float tf[4][160];
    __shared__ float vsh[4][128];
    int wv = threadIdx.x >> 6, lane = threadIdx.x & 63;
    int e = blockIdx.x * 4 + wv;
    int row = edge_index[e], col = edge_index[E_ + e];
    if (lane < 16) {
        int c = lane >> 2, f = lane & 3;
        float rj = 0.f;
#pragma unroll
        for (int x = 0; x < 3; ++x) {
            float a = coord[(size_t)row * 12 + c * 3 + x] - coord[(size_t)col * 12 + c * 3 + x];
            float b = coord[(size_t)row * 12 + f * 3 + x] - coord[(size_t)col * 12 + f * 3 + x];
            rj += a * b;
        }
        tf[wv][lane] = rj;
    }
    for (int f = lane; f < 128; f += 64) tf[wv][16 + f] = h[(size_t)col * 128 + f];
    if (lane >= 48) tf[wv][144 + lane - 48] = edge_attr[(size_t)e * 16 + lane - 48];
    __syncthreads();
    float v0 = bkv[2 * lane + 1], v1 = bkv[2 * (64 + lane) + 1];
    for (int f = 0; f < 160; ++f) {
        float tfv = tf[wv][f];
        v0 += tfv * Wkv[f * 256 + 2 * lane + 1];
        v1 += tfv * Wkv[f * 256 + 129 + 2 * lane];
    }
    float att = __expf(alpha[e] - fdec(m[row])) / s[row];
    atomicAdd(&agg[(size_t)row * 128 + lane], att * v0);
    atomicAdd(&agg[(size_t)row * 128 + 64 + lane], att * v1);
    vsh[wv][lane] = v0;
    vsh[wv][64 + lane] = v1;
    __syncthreads();
    float cv[4] = {0.f, 0.f, 0.f, 0.f};
    for (int g = 0; g < 8; ++g) {
        int jc = g * 64 + lane;
        float u = 0.f;
        for (int dd = 0; dd < 128; ++dd) u += vsh[wv][dd] * Wc1[dd * 512 + jc];
        float su = u / (1.f + __expf(-u));
#pragma unroll
        for (int c = 0; c < 4; ++c) cv[c] += su * Wc2[jc * 4 + c];
    }
#pragma unroll
    for (int mm = 32; mm; mm >>= 1)
#pragma unroll
        for (int c = 0; c < 4; ++c) cv[c] += __shfl_xor(cv[c], mm);
    if (lane < 12) {
        int c = lane / 3;
        float cd = coord[(size_t)row * 12 + lane] - coord[(size_t)col * 12 + lane];
        atomicAdd(&cagg[(size_t)row * 12 + lane], att * cv[c] * cd);
    }
    if (lane == 0) att_out[e] = att;
}

__global__ __launch_bounds__(256) void k_final_slow(
    const float* __restrict__ h, const float* __restrict__ coord,
    const float* __restrict__ agg, const float* __restrict__ cagg,
    float* __restrict__ h_out, float* __restrict__ coord_out) {
    int idx = blockIdx.x * 256 + threadIdx.x;
    h_out[idx] = h[idx] + agg[idx];
    if (idx < N_ * 12) {
        float v = fminf(fmaxf(cagg[idx], -10.f), 10.f);
        coord_out[idx] = coord[idx] + v;
    }
}

// ---------------------------------------------------------------- launch
extern "C" void kernel_launch(void* const* d_in, const int* in_sizes, int n_in,
                              void* d_out, int out_size, void* d_ws, size_t ws_size,
                              hipStream_t stream) {
    (void)in_sizes; (void)n_in; (void)out_size;
    const float* h          = (const float*)d_in[0];
    const float* coord      = (const float*)d_in[1];
    const int*   edge_index = (const int*)d_in[2];
    const float* edge_attr  = (const float*)d_in[3];
    const float* Wq         = (const float*)d_in[4];
    const float* bq         = (const float*)d_in[5];
    const float* Wkv        = (const float*)d_in[6];
    const float* bkv        = (const float*)d_in[7];
    const float* Wc1        = (const float*)d_in[8];
    const float* Wc2        = (const float*)d_in[9];

    float* out = (float*)d_out;
    float* h_out = out;
    float* coord_out = out + (size_t)N_ * 128;
    float* att_out = coord_out + (size_t)N_ * 12;

    char* w = (char*)d_ws;
    size_t off = 0;
    auto alloc = [&](size_t bytes) -> void* {
        void* p = w + off;
        off += (bytes + 255) & ~(size_t)255;
        return p;
    };
    // ---- fast-path layout (counts as one contiguous 2N block — round-10 bug)
    int* countsR   = (int*)alloc((size_t)2 * N_ * 4);      // zeroed as a whole
    int* countsC   = countsR + N_;
    float* hq      = (float*)alloc((size_t)N_ * 128 * 4);
    float* k_h     = (float*)alloc((size_t)N_ * 128 * 4);
    u16*   v_h16   = (u16*)alloc((size_t)N_ * 128 * 2);    // = v_hi
    u16*   v_lo16  = (u16*)alloc((size_t)N_ * 128 * 2);
    u16*   vWc1s   = (u16*)alloc((size_t)N_ * 512 * 2);    // swizzled (jc&15)*32+(jc>>4)
    float* hqWkr   = (float*)alloc((size_t)N_ * 16 * 4);
    float* hqWkea  = (float*)alloc((size_t)N_ * 16 * 4);
    float* alphaP  = (float*)alloc((size_t)E_ * 4);        // by row-CSR position
    float* Z       = (float*)alloc((size_t)E_ * 4 * 4);    // by edge id
    float* Cr      = (float*)alloc(16 * 512 * 4);
    float* Cea     = (float*)alloc(16 * 512 * 4);
    float* M_r     = (float*)alloc(128 * 16 * 4);
    float* M_ea    = (float*)alloc(128 * 16 * 4);
    float* br      = (float*)alloc(16 * 4);
    float* bea     = (float*)alloc(16 * 4);
    u16* WAf_hi    = (u16*)alloc((size_t)26 * 4 * 64 * 8 * 2);
    u16* WAf_lo    = (u16*)alloc((size_t)26 * 4 * 64 * 8 * 2);
    u16* Wc1f_hi   = (u16*)alloc((size_t)32 * 4 * 64 * 8 * 2);
    u16* Wc1f_lo   = (u16*)alloc((size_t)32 * 4 * 64 * 8 * 2);
    int* offsetsR  = (int*)alloc((size_t)(N_ + 1) * 4);
    int* cursorR   = (int*)alloc((size_t)N_ * 4);
    int* edge_ids  = (int*)alloc((size_t)E_ * 4);
    int* offsetsC  = (int*)alloc((size_t)(N_ + 1) * 4);
    int* cursorC   = (int*)alloc((size_t)N_ * 4);
    int* edge_ids2 = (int*)alloc((size_t)E_ * 4);
    size_t fast_req = off;

    if (ws_size >= fast_req) {
        hipLaunchKernelGGL(k_zero, dim3((2 * N_ + 255) / 256), dim3(256), 0, stream,
                           (unsigned int*)countsR, 2 * N_);
        hipLaunchKernelGGL(k_hist_both, dim3((E_ + 255) / 256), dim3(256), 0, stream,
                           edge_index, countsR, countsC);
        hipLaunchKernelGGL(k_scan2, dim3(1), dim3(1024), 0, stream,
                           countsR, countsC, offsetsR, cursorR, offsetsC, cursorC);
        hipLaunchKernelGGL(k_fill_both, dim3((E_ + 255) / 256), dim3(256), 0, stream,
                           edge_index, cursorR, cursorC, edge_ids, edge_ids2);
        hipLaunchKernelGGL(k_prep0, dim3(17), dim3(256), 0, stream,
                           Wq, bq, Wkv, M_r, M_ea, br, bea);
        hipLaunchKernelGGL(k_prepA, dim3(26), dim3(256), 0, stream,
                           Wq, Wkv, M_r, M_ea, WAf_hi, WAf_lo);
        hipLaunchKernelGGL(k_prepB, dim3(32), dim3(256), 0, stream,
                           Wc1, Wc1f_hi, Wc1f_lo);
        hipLaunchKernelGGL(k_composites, dim3(64), dim3(256), 0, stream, Wkv, Wc1, Cr, Cea);
        hipLaunchKernelGGL(k_gemmA, dim3(N_ / 16), dim3(256), 0, stream,
                           h, WAf_hi, WAf_lo, bq, bkv, br, bea,
                           hq, k_h, v_h16, v_lo16, hqWkr, hqWkea);
        hipLaunchKernelGGL(k_gemmB, dim3(N_ / 16), dim3(256), 0, stream,
                           v_h16, v_lo16, Wc1f_hi, Wc1f_lo, vWc1s);
        hipLaunchKernelGGL(k_alpha_csr, dim3(E_ / 4), dim3(256), 0, stream,
                           edge_index, edge_ids, coord, edge_attr, hq, k_h, hqWkr, hqWkea, alphaP);
        hipLaunchKernelGGL(k_edge_z, dim3(768), dim3(256), 0, stream,
                           edge_index, edge_ids2, coord, edge_attr, Cr, Cea, Wc2, vWc1s, Z);
        hipLaunchKernelGGL(k_node_main, dim3(N_ / 4), dim3(256), 0, stream,
                           edge_index, offsetsR, edge_ids, alphaP, v_h16, Z,
                           coord, edge_attr, h, Wkv, h_out, coord_out, att_out);
    } else {
        // ---- slow validated path (separate layout from offset 0)
        off = 0;
        float* s        = (float*)alloc((size_t)N_ * 4);
        unsigned int* m = (unsigned int*)alloc((size_t)N_ * 4);
        float* agg      = (float*)alloc((size_t)N_ * 128 * 4);
        float* cagg     = (float*)alloc((size_t)N_ * 12 * 4);
        size_t zb       = off;
        float* hq2      = (float*)alloc((size_t)N_ * 128 * 4);
        float* alpha2   = (float*)alloc((size_t)E_ * 4);
        int zero_n = (int)(zb / 4);
        hipLaunchKernelGGL(k_zero, dim3((zero_n + 255) / 256), dim3(256), 0, stream,
                           (unsigned int*)s, zero_n);
        hipLaunchKernelGGL(k_hq_slow, dim3(N_ * 128 / 256), dim3(256), 0, stream, h, Wq, bq, hq2);
        hipLaunchKernelGGL(k_alpha_slow, dim3(E_ / 4), dim3(256), 0, stream,
                           edge_index, coord, edge_attr, h, Wkv, bkv, hq2, alpha2, m);
        hipLaunchKernelGGL(k_expsum_slow, dim3((E_ + 255) / 256), dim3(256), 0, stream,
                           edge_index, alpha2, m, s);
        hipLaunchKernelGGL(k_edge2_slow, dim3(E_ / 4), dim3(256), 0, stream,
                           edge_index, coord, edge_attr, h, Wkv, bkv, Wc1, Wc2,
                           alpha2, m, s, agg, cagg, att_out);
        hipLaunchKernelGGL(k_final_slow, dim3(N_ * 128 / 256), dim3(256), 0, stream,
                           h, coord, agg, cagg, h_out, coord_out);
    }
}